// Round 12
// baseline (1198.039 us; speedup 1.0000x reference)
//
#include <hip/hip_runtime.h>
#include <cfloat>

#define BN 16384   // B*N = 2*8192

// ---------------- workspace layout (float words) ----------------
#define WOFF_WT    0
#define WOFF_P1M   4096
#define WOFF_G1M   8192
#define WOFF_MMT   12288
#define WOFF_WD2T  16384
#define WOFF_G2T   20480
#define WOFF_WDN   24576
#define WOFF_WAL   28672
#define WOFF_WD1   32768
#define WOFF_BT    33024
#define WOFF_BAL   33088
#define WOFF_VC    33152
#define WOFF_UD1   33216
#define WOFF_UD2   33280
#define WOFF_UDN   33344
// bf16-packed (u32 pair) row-major weight copies for MFMA (filled by k0b)
#define WOFF_WMB   33792   // Wm  [c][cp] 2048 u32
#define WOFF_WD2B  35840   // Wd2s[c][cp] 2048 u32
#define WOFF_G2B   37888   // G2s [c][cp] 2048 u32
#define WB         39936

static constexpr size_t OFF_P1   = WB;                           // [BN][64]
static constexpr size_t OFF_G1   = OFF_P1 + (size_t)BN*64;       // [BN][64]
static constexpr size_t OFF_AL   = OFF_G1 + (size_t)BN*64;       // [BN][64]
static constexpr size_t OFF_R1   = OFF_AL + (size_t)BN*64;       // [BN][64]
static constexpr size_t OFF_P4   = OFF_R1 + (size_t)BN*64;       // [BN] float4 (x,y,z,sq)
static constexpr size_t OFF_IDX  = OFF_P4 + (size_t)BN*4;        // [BN][16] int
static constexpr size_t OFF_Y    = OFF_IDX + (size_t)BN*16;      // [BN][64]

struct P32 { const float* a[32]; };

#define WSWZ(i,o) ((o) ^ (((i)&7)<<2))

typedef __attribute__((ext_vector_type(8))) short bf16x8;
typedef __attribute__((ext_vector_type(4))) float f32x4;

__device__ __forceinline__ unsigned bf2(float lo, float hi) {
  unsigned a = __float_as_uint(lo); a = (a + 0x7fffu + ((a>>16)&1u)) >> 16;
  unsigned b = __float_as_uint(hi); b = (b + 0x7fffu + ((b>>16)&1u)) & 0xffff0000u;
  return a | b;
}

// =============== K0: fold weights ===============
__global__ __launch_bounds__(256) void k0_fold(P32 P, float* __restrict__ ws)
{
  const int bid = blockIdx.x, tid = threadIdx.x;
  const float* Wtop = P.a[2];  const float* btop = P.a[3];
  const float* stop = P.a[4];  const float* ttop = P.a[5];
  const float* Wphi = P.a[6];  const float* bphi = P.a[7];
  const float* Wpsi = P.a[8];  const float* bpsi = P.a[9];
  const float* Wal  = P.a[10]; const float* bal  = P.a[11];
  const float* Wg1  = P.a[12]; const float* bg1  = P.a[13];
  const float* sg1  = P.a[14]; const float* tg1  = P.a[15];
  const float* Wg2  = P.a[16];
  const float* sg2  = P.a[18];
  const float* Wd1  = P.a[20]; const float* bd1  = P.a[21];
  const float* sd1  = P.a[22]; const float* td1  = P.a[23];
  const float* Wd2  = P.a[24]; const float* bd2  = P.a[25];
  const float* sd2  = P.a[26]; const float* td2  = P.a[27];
  const float* Wdn  = P.a[28]; const float* bdn  = P.a[29];
  const float* sdn  = P.a[30]; const float* tdn  = P.a[31];

  if (bid == 0) {
    for (int e = tid; e < 4096; e += 256) { int o = e >> 6; ws[WOFF_WT + e] = stop[o]*Wtop[e]; }
    if (tid < 64) {
      ws[WOFF_BT  + tid] = stop[tid]*btop[tid] + ttop[tid];
      ws[WOFF_BAL + tid] = bal[tid];
      ws[WOFF_UD1 + tid] = sd1[tid]*bd1[tid] + td1[tid];
      ws[WOFF_UD2 + tid] = sd2[tid]*bd2[tid] + td2[tid];
      ws[WOFF_UDN + tid] = sdn[tid]*bdn[tid] + tdn[tid];
      float acc = 0.f;
      for (int c = 0; c < 64; ++c)
        acc += Wg1[tid*64+c] * (bphi[c] - bpsi[c] + sd2[c]*bd2[c] + td2[c]);
      ws[WOFF_VC + tid] = sg1[tid]*(acc + bg1[tid]) + tg1[tid];
    }
  } else if (bid == 1) {          // P1m[o][i] = s_g1[o] * (Wg1 Wphi)[o][i]
    for (int e = tid; e < 4096; e += 256) {
      int o = e >> 6, i = e & 63; float a = 0.f;
      for (int c = 0; c < 64; ++c) a += Wg1[o*64+c]*Wphi[c*64+i];
      ws[WOFF_P1M + e] = sg1[o]*a;
    }
  } else if (bid == 2) {          // G1m
    for (int e = tid; e < 4096; e += 256) {
      int o = e >> 6, i = e & 63; float a = 0.f;
      for (int c = 0; c < 64; ++c) a += Wg1[o*64+c]*Wpsi[c*64+i];
      ws[WOFF_G1M + e] = sg1[o]*a;
    }
  } else if (bid == 3) {          // MmT[cp][c] = s_g1[c] * (Wg1 diag(sd2) Wd2)[c][cp]
    for (int e = tid; e < 4096; e += 256) {
      int cp = e >> 6, c = e & 63; float a = 0.f;
      for (int u = 0; u < 64; ++u) a += Wg1[c*64+u]*sd2[u]*Wd2[u*64+cp];
      ws[WOFF_MMT + e] = sg1[c]*a;
    }
  } else if (bid == 4) {          // Wd2T[cp][c] ; Wd1f
    for (int e = tid; e < 4096; e += 256) {
      int cp = e >> 6, c = e & 63;
      ws[WOFF_WD2T + e] = sd2[c]*Wd2[c*64+cp];
    }
    if (tid < 192) ws[WOFF_WD1 + tid] = sd1[tid/3]*Wd1[tid];
  } else if (bid == 5) {          // G2T[cp][c]
    for (int e = tid; e < 4096; e += 256) {
      int cp = e >> 6, c = e & 63;
      ws[WOFF_G2T + e] = sg2[c]*Wg2[c*64+cp];
    }
  } else if (bid == 6) {          // Wdn row-major
    for (int e = tid; e < 4096; e += 256) { int o = e >> 6; ws[WOFF_WDN + e] = sdn[o]*Wdn[e]; }
  } else {                        // W_alpha copy
    for (int e = tid; e < 4096; e += 256) ws[WOFF_WAL + e] = Wal[e];
  }
}

// =============== K0b: pack MFMA weights to bf16 row-major [c][cp] ===============
__global__ __launch_bounds__(256) void k0b_pack(float* __restrict__ ws)
{
  const int m = blockIdx.x;                    // 0:Wm 1:Wd2s 2:G2s
  const int srcO = (m==0) ? WOFF_MMT : (m==1) ? WOFF_WD2T : WOFF_G2T;   // [cp][c] fp32
  const int dstO = (m==0) ? WOFF_WMB : (m==1) ? WOFF_WD2B : WOFF_G2B;   // [c][cp] bf16 pairs
  unsigned* dst = (unsigned*)&ws[dstO];
  for (int w = threadIdx.x; w < 2048; w += 256) {
    int c = w >> 5, pair = w & 31;
    float v0 = ws[srcO + (pair*2  )*64 + c];
    float v1 = ws[srcO + (pair*2+1)*64 + c];
    dst[w] = bf2(v0, v1);
  }
}

// =============== K1: per-point features (x -> P1,G1,AL) + r1 + p4 ===============
__global__ __launch_bounds__(256) void k1_feat(const float* __restrict__ inp,
                                               const float* __restrict__ inx,
                                               float* __restrict__ ws)
{
  __shared__ float tX[64][16];   // [c][pt]
  __shared__ float wT[64][64];   // transposed + swizzled weights
  const int tid = threadIdx.x;
  const int pt = tid & 15, q = tid >> 4;   // q in [0,16): channels q*4..q*4+3
  const int gid0 = blockIdx.x * 16;
  const int b = gid0 >> 13, n0 = gid0 & 8191;
  const size_t gq = (size_t)gid0 + pt;

  for (int r = tid; r < 1024; r += 256) {
    int c = r >> 4, col = r & 15;
    tX[c][col] = inx[((size_t)(b*64 + c) << 13) + n0 + col];
  }
  for (int r = tid; r < 4096; r += 256) {
    int o = r >> 6, i = r & 63;
    wT[i][WSWZ(i,o)] = ws[WOFF_WT + r];
  }
  __syncthreads();

  float acc[4];
  #pragma unroll
  for (int i = 0; i < 4; ++i) acc[i] = ws[WOFF_BT + q*4 + i];
  for (int ci = 0; ci < 64; ++ci) {
    float xv = tX[ci][pt];
    const float4 w4 = *(const float4*)&wT[ci][WSWZ(ci, q*4)];
    acc[0] = fmaf(w4.x, xv, acc[0]);
    acc[1] = fmaf(w4.y, xv, acc[1]);
    acc[2] = fmaf(w4.z, xv, acc[2]);
    acc[3] = fmaf(w4.w, xv, acc[3]);
  }
  __syncthreads();
  #pragma unroll
  for (int i = 0; i < 4; ++i) tX[q*4 + i][pt] = acc[i];

  // p4 + r1 (global only)
  {
    size_t pb = (size_t)b*3*8192 + n0 + pt;
    float px = inp[pb], py = inp[pb + 8192], pz = inp[pb + 16384];
    float sq = __fadd_rn(__fadd_rn(__fmul_rn(px,px), __fmul_rn(py,py)), __fmul_rn(pz,pz));
    if (q == 0) *(float4*)&ws[OFF_P4 + gq*4] = make_float4(px,py,pz,sq);
    float r1v[4];
    #pragma unroll
    for (int i = 0; i < 4; ++i) {
      int c = q*4 + i;
      float a = ws[WOFF_WD1 + c*3+0]*px;
      a = fmaf(ws[WOFF_WD1 + c*3+1], py, a);
      a = fmaf(ws[WOFF_WD1 + c*3+2], pz, a);
      r1v[i] = a;
    }
    *(float4*)&ws[OFF_R1 + gq*64 + q*4] = make_float4(r1v[0], r1v[1], r1v[2], r1v[3]);
  }
  __syncthreads();

  #pragma unroll
  for (int m = 0; m < 3; ++m) {
    const int    mof = (m==0) ? WOFF_P1M : (m==1) ? WOFF_G1M : WOFF_WAL;
    const size_t oof = (m==0) ? OFF_P1   : (m==1) ? OFF_G1   : OFF_AL;
    __syncthreads();
    for (int r = tid; r < 4096; r += 256) {
      int o = r >> 6, i = r & 63;
      wT[i][WSWZ(i,o)] = ws[mof + r];
    }
    __syncthreads();
    #pragma unroll
    for (int i = 0; i < 4; ++i) acc[i] = (m == 2) ? ws[WOFF_BAL + q*4 + i] : 0.f;
    for (int ci = 0; ci < 64; ++ci) {
      float xv = tX[ci][pt];
      const float4 w4 = *(const float4*)&wT[ci][WSWZ(ci, q*4)];
      acc[0] = fmaf(w4.x, xv, acc[0]);
      acc[1] = fmaf(w4.y, xv, acc[1]);
      acc[2] = fmaf(w4.z, xv, acc[2]);
      acc[3] = fmaf(w4.w, xv, acc[3]);
    }
    *(float4*)&ws[oof + gq*64 + q*4] = make_float4(acc[0], acc[1], acc[2], acc[3]);
  }
}

// numpy-exact distance
__device__ __forceinline__ float pdist(const float4 q4, const float4 c4) {
  float m = __fadd_rn(__fadd_rn(__fmul_rn(q4.x,c4.x), __fmul_rn(q4.y,c4.y)), __fmul_rn(q4.z,c4.z));
  return __fsub_rn(__fadd_rn(q4.w, c4.w), __fmul_rn(2.f, m));
}

__device__ __forceinline__ unsigned dmono(float d) {
  unsigned db = __float_as_uint(d);
  return db ^ (((int)db < 0) ? 0xffffffffu : 0x80000000u);
}

// branchless sorted insert into 4-slot ascending register list (u64 keys)
__device__ __forceinline__ void ins4(unsigned long long& k0, unsigned long long& k1,
                                     unsigned long long& k2, unsigned long long& k3,
                                     unsigned long long x)
{
  unsigned long long t;
  t = (k0 < x) ? k0 : x;  x = (k0 < x) ? x : k0;  k0 = t;
  t = (k1 < x) ? k1 : x;  x = (k1 < x) ? x : k1;  k1 = t;
  t = (k2 < x) ? k2 : x;  x = (k2 < x) ? x : k2;  k2 = t;
  k3 = (k3 < x) ? k3 : x;
}

// =============== K2: exact top-16 KNN, single pass (wave-per-query) ===============
// Each lane keeps its exact top-4 (u64 key = dmono(d)<<32 | idx) of its 128-candidate
// stream in registers (branchless bubble insert -- no cross-lane ops in the scan).
// The 256-key union is then reduced by 16 wave-argmin rounds (exact lex-(d,idx)).
// SOUNDNESS: every key a lane dropped is > its kept 4th-smallest (saved k3). If all
// lanes' saved k3 >= m16 (16th of union), the union contains the true top-16 -> exact.
// Else (P ~ 4e-6/query) fall back to the proven serial rescan.
__global__ __launch_bounds__(256) void k2_topk(float* __restrict__ ws)
{
  __shared__ float4 tile[1024];   // 16 KB
  const int tid = threadIdx.x;
  const int lane = tid & 63, w = tid >> 6;
  const int gid = blockIdx.x*4 + w;
  const int b = gid >> 13;
  const float4 q4 = *(const float4*)&ws[OFF_P4 + (size_t)gid*4];
  const float4* cp4 = (const float4*)&ws[OFF_P4 + (size_t)b*8192*4];
  int* ib = (int*)&ws[OFF_IDX];

  unsigned long long k0=~0ull, k1=~0ull, k2=~0ull, k3=~0ull;

  #pragma unroll 1
  for (int c0 = 0; c0 < 8192; c0 += 1024) {
    __syncthreads();
    #pragma unroll
    for (int t = 0; t < 4; ++t) tile[tid + t*256] = cp4[c0 + tid + t*256];
    __syncthreads();
    #pragma unroll 1
    for (int r = 0; r < 16; ++r) {
      const int ci = r*64 + lane;
      float d = pdist(q4, tile[ci]);
      unsigned long long x = ((unsigned long long)dmono(d) << 32) | (unsigned)(c0 + ci);
      ins4(k0, k1, k2, k3, x);
    }
  }

  const unsigned long long savedk3 = k3;

  // 16 wave-argmin rounds over the 256-key union (4 keys/lane)
  unsigned myres = 0u;
  unsigned long long m = 0ull;
  #pragma unroll 1
  for (int r = 0; r < 16; ++r) {
    unsigned long long a01 = (k0 < k1) ? k0 : k1;
    unsigned long long a23 = (k2 < k3) ? k2 : k3;
    m = (a01 < a23) ? a01 : a23;
    #pragma unroll
    for (int s = 1; s < 64; s <<= 1) {
      unsigned long long o = __shfl_xor(m, s);
      m = (o < m) ? o : m;
    }
    k0 = (k0 == m) ? ~0ull : k0;  k1 = (k1 == m) ? ~0ull : k1;
    k2 = (k2 == m) ? ~0ull : k2;  k3 = (k3 == m) ? ~0ull : k3;
    if (lane == r) myres = (unsigned)(m & 0xffffffffu);
  }

  // safety check: m (last round) is the 16th-smallest of the union
  const bool unsafe = __ballot(savedk3 < m) != 0ull;
  if (!unsafe) {
    if (lane < 16) ib[(size_t)gid*16 + lane] = (int)myres;
  } else {
    // guaranteed-correct fallback (~4e-6 per query): serial rescan
    if (lane == 0) {
      float ds[16]; int is[16];
      #pragma unroll
      for (int r = 0; r < 16; ++r) { ds[r] = FLT_MAX; is[r] = 0x7fffffff; }
      for (int t = 0; t < 8192; ++t) {
        float d = pdist(q4, cp4[t]);
        if (d < ds[15]) {
          #pragma unroll
          for (int s = 15; s >= 0; --s) {
            bool bs = d < ds[s];
            bool bm = (s > 0) ? (d < ds[s-1]) : false;
            float dn = bs ? (bm ? ds[s-1] : d) : ds[s];
            int   jn = bs ? (bm ? is[s-1] : t) : is[s];
            ds[s] = dn; is[s] = jn;
          }
        }
      }
      #pragma unroll
      for (int r = 0; r < 16; ++r) ib[(size_t)gid*16 + r] = is[r];
    }
  }
}

// =============== K3 (MFMA): fused per-point block (weights in LDS) ===============
// 8 points/block (was 16): hL 16 KB, total LDS 40 KB -> 4 blocks/CU for the
// gather-latency-bound phase. Arithmetic identical per point (bit-for-bit).
__global__ __launch_bounds__(256) void k3_mfma(float* __restrict__ ws, float* __restrict__ out)
{
  __shared__ __align__(16) unsigned char wL[24576];  // 3 x [64 c][64 cp] bf16, swizzled
  __shared__ __align__(16) unsigned char hL[16384];  // [128 col][64 cp] bf16, swizzled
  const int tid = threadIdx.x;
  const int lane = tid & 63, wid = tid >> 6;
  const int l15 = lane & 15, hi = lane >> 4;
  const int gid0 = blockIdx.x * 8;        // first global point of block
  const int b = gid0 >> 13;
  const int n0 = gid0 & 8191;

  // ---- stage bf16 weights into LDS (swizzled rows) ----
  {
    const uint4* wsrc = (const uint4*)&ws[WOFF_WMB];
    for (int t = tid; t < 1536; t += 256) {
      int m = t >> 9, r = t & 511;
      int c = r >> 3, q = r & 7;
      uint4 v = wsrc[t];
      *(uint4*)(wL + m*8192 + ((c*128 + q*16) ^ ((c&7)<<4))) = v;
    }
  }
  // ---- compute h for own column (col = tid, first 128 threads) ----
  if (tid < 128) {
    const int pt = tid >> 4, kq = tid & 15;
    const size_t gq = (size_t)gid0 + pt;
    const int jh = ((const int*)&ws[OFF_IDX])[gq*16 + kq];
    const size_t gjh = (size_t)b*8192 + jh;
    const float4* Ar = (const float4*)&ws[OFF_R1 + gq*64];
    const float4* Br = (const float4*)&ws[OFF_R1 + gjh*64];
    const float4* Ur = (const float4*)&ws[WOFF_UD1];
    const int swzh = (tid & 7) << 4;
    #pragma unroll
    for (int t = 0; t < 16; ++t) {
      float4 a = Ar[t], bb = Br[t], u = Ur[t];
      float v0 = fmaxf(a.x - bb.x + u.x, 0.f);
      float v1 = fmaxf(a.y - bb.y + u.y, 0.f);
      float v2 = fmaxf(a.z - bb.z + u.z, 0.f);
      float v3 = fmaxf(a.w - bb.w + u.w, 0.f);
      *(uint2*)(hL + ((tid*128 + t*8) ^ swzh)) = make_uint2(bf2(v0,v1), bf2(v2,v3));
    }
  }
  __syncthreads();

  float* attnp = out + (size_t)2*64*8192;   // attn region after out0
  const f32x4 zf = {0.f, 0.f, 0.f, 0.f};

  #pragma unroll 1
  for (int i = 0; i < 2; ++i) {
    const int ct = (wid << 1) + i;          // coltile == point index in block (0..7)
    const int n = n0 + ct;
    const size_t gqc = (size_t)gid0 + ct;
    const int mycol = (ct << 4) + l15;      // 0..127
    const int swz = (mycol & 7) << 4;
    const int hbase = mycol*128 + hi*16;
    bf16x8 hb0 = *(const bf16x8*)(hL + ((hbase     ) ^ swz));
    bf16x8 hb1 = *(const bf16x8*)(hL + ((hbase + 64) ^ swz));
    const int jj = ((const int*)&ws[OFF_IDX])[gqc*16 + l15];
    const size_t gjc = (size_t)b*8192 + jj;

    // ---- D-GEMM (pos) + M-GEMM ----
    f32x4 accD[4], accM[4];
    #pragma unroll
    for (int rt = 0; rt < 4; ++rt) { accD[rt] = zf; accM[rt] = zf; }
    #pragma unroll
    for (int rt = 0; rt < 4; ++rt) {
      const int c = (rt << 4) + l15;
      const int ws2 = (c & 7) << 4;
      const int wb = c*128 + hi*16;
      bf16x8 m0 = *(const bf16x8*)(wL + (((wb     ) ^ ws2)));
      bf16x8 m1 = *(const bf16x8*)(wL + (((wb + 64) ^ ws2)));
      bf16x8 d0 = *(const bf16x8*)(wL + (8192 + ((wb     ) ^ ws2)));
      bf16x8 d1 = *(const bf16x8*)(wL + (8192 + ((wb + 64) ^ ws2)));
      accM[rt] = __builtin_amdgcn_mfma_f32_16x16x32_bf16(m0, hb0, accM[rt], 0, 0, 0);
      accM[rt] = __builtin_amdgcn_mfma_f32_16x16x32_bf16(m1, hb1, accM[rt], 0, 0, 0);
      accD[rt] = __builtin_amdgcn_mfma_f32_16x16x32_bf16(d0, hb0, accD[rt], 0, 0, 0);
      accD[rt] = __builtin_amdgcn_mfma_f32_16x16x32_bf16(d1, hb1, accD[rt], 0, 0, 0);
    }

    // ---- hg = relu(aM + P1[n] - G1[j] + vc), write bf16 back into hL (in place) ----
    #pragma unroll
    for (int rt = 0; rt < 4; ++rt) {
      const int c0 = (rt << 4) + (hi << 2);
      const float4 p1 = *(const float4*)&ws[OFF_P1 + gqc*64 + c0];
      const float4 g1 = *(const float4*)&ws[OFF_G1 + gjc*64 + c0];
      const float4 vc = *(const float4*)&ws[WOFF_VC + c0];
      float h0 = fmaxf(accM[rt][0] + p1.x - g1.x + vc.x, 0.f);
      float h1 = fmaxf(accM[rt][1] + p1.y - g1.y + vc.y, 0.f);
      float h2 = fmaxf(accM[rt][2] + p1.z - g1.z + vc.z, 0.f);
      float h3 = fmaxf(accM[rt][3] + p1.w - g1.w + vc.w, 0.f);
      *(uint2*)(hL + ((mycol*128 + (c0 << 1)) ^ swz)) = make_uint2(bf2(h0,h1), bf2(h2,h3));
    }

    // ---- G2-GEMM on hg (wave-local; DS ops are in-order within a wave) ----
    bf16x8 gb0 = *(const bf16x8*)(hL + ((hbase     ) ^ swz));
    bf16x8 gb1 = *(const bf16x8*)(hL + ((hbase + 64) ^ swz));
    f32x4 accG[4];
    #pragma unroll
    for (int rt = 0; rt < 4; ++rt) accG[rt] = zf;
    #pragma unroll
    for (int rt = 0; rt < 4; ++rt) {
      const int c = (rt << 4) + l15;
      const int ws2 = (c & 7) << 4;
      const int wb = c*128 + hi*16;
      bf16x8 g0 = *(const bf16x8*)(wL + (16384 + ((wb     ) ^ ws2)));
      bf16x8 g1f = *(const bf16x8*)(wL + (16384 + ((wb + 64) ^ ws2)));
      accG[rt] = __builtin_amdgcn_mfma_f32_16x16x32_bf16(g0,  gb0, accG[rt], 0, 0, 0);
      accG[rt] = __builtin_amdgcn_mfma_f32_16x16x32_bf16(g1f, gb1, accG[rt], 0, 0, 0);
    }

    // ---- softmax over kk (lane&15), attn store, y reduce ----
    #pragma unroll
    for (int rt = 0; rt < 4; ++rt) {
      const int c0 = (rt << 4) + (hi << 2);
      const float4 al = *(const float4*)&ws[OFF_AL + gjc*64 + c0];
      const float4 u2 = *(const float4*)&ws[WOFF_UD2 + c0];
      float y4[4];
      #pragma unroll
      for (int r = 0; r < 4; ++r) {
        float g = accG[rt][r];
        float mx = g;
        mx = fmaxf(mx, __shfl_xor(mx, 1));
        mx = fmaxf(mx, __shfl_xor(mx, 2));
        mx = fmaxf(mx, __shfl_xor(mx, 4));
        mx = fmaxf(mx, __shfl_xor(mx, 8));
        float e = __expf(g - mx);
        float sm = e;
        sm += __shfl_xor(sm, 1);
        sm += __shfl_xor(sm, 2);
        sm += __shfl_xor(sm, 4);
        sm += __shfl_xor(sm, 8);
        float rs;
        asm("v_rcp_f32 %0, %1" : "=v"(rs) : "v"(sm));
        float a = e * rs;
        attnp[(((size_t)(b*64 + c0 + r) << 13) + n)*16 + l15] = a;
        float pv = ((const float*)&al)[r] + accD[rt][r] + ((const float*)&u2)[r];
        float yv = a * pv;
        yv += __shfl_xor(yv, 1);
        yv += __shfl_xor(yv, 2);
        yv += __shfl_xor(yv, 4);
        yv += __shfl_xor(yv, 8);
        y4[r] = yv;
      }
      if (l15 == 0)
        *(float4*)&ws[OFF_Y + gqc*64 + c0] = make_float4(y4[0], y4[1], y4[2], y4[3]);
    }
  }
}

// =============== K4: out = Wdn*y + udn + input_x ===============
__global__ __launch_bounds__(256) void k4_out(const float* __restrict__ inx,
                                              float* __restrict__ ws,
                                              float* __restrict__ out)
{
  __shared__ float yS[16][64];
  __shared__ float wT[64][64];
  const int tid = threadIdx.x;
  const int pt = tid & 15, q = tid >> 4;   // channels q*4..q*4+3
  const int gid0 = blockIdx.x*16;
  const int b = gid0 >> 13, n0 = gid0 & 8191;
  for (int r = tid; r < 1024; r += 256) {
    int p2 = r >> 6, c = r & 63;
    yS[p2][c ^ p2] = ws[OFF_Y + (size_t)(gid0 + p2)*64 + c];
  }
  for (int r = tid; r < 4096; r += 256) {
    int o = r >> 6, i = r & 63;
    wT[i][WSWZ(i,o)] = ws[WOFF_WDN + r];
  }
  __syncthreads();
  float acc[4];
  #pragma unroll
  for (int i = 0; i < 4; ++i) acc[i] = ws[WOFF_UDN + q*4 + i];
  for (int ci = 0; ci < 64; ++ci) {
    float yv = yS[pt][ci ^ pt];
    const float4 w4 = *(const float4*)&wT[ci][WSWZ(ci, q*4)];
    acc[0] = fmaf(w4.x, yv, acc[0]);
    acc[1] = fmaf(w4.y, yv, acc[1]);
    acc[2] = fmaf(w4.z, yv, acc[2]);
    acc[3] = fmaf(w4.w, yv, acc[3]);
  }
  #pragma unroll
  for (int i = 0; i < 4; ++i) {
    const int c = q*4 + i;
    size_t o = ((size_t)(b*64 + c) << 13) + n0 + pt;
    out[o] = acc[i] + inx[o];
  }
}

extern "C" void kernel_launch(void* const* d_in, const int* in_sizes, int n_in,
                              void* d_out, int out_size, void* d_ws, size_t ws_size,
                              hipStream_t stream)
{
  (void)in_sizes; (void)n_in; (void)out_size; (void)ws_size;
  float* ws = (float*)d_ws;
  const float* inp = (const float*)d_in[0];
  const float* inx = (const float*)d_in[1];
  float* out = (float*)d_out;
  P32 P;
  for (int i = 0; i < 32; ++i) P.a[i] = (const float*)d_in[i];

  k0_fold   <<<8,      256, 0, stream>>>(P, ws);
  k0b_pack  <<<3,      256, 0, stream>>>(ws);
  k1_feat   <<<BN/16,  256, 0, stream>>>(inp, inx, ws);
  k2_topk   <<<BN/4,   256, 0, stream>>>(ws);
  k3_mfma   <<<BN/8,   256, 0, stream>>>(ws, out);
  k4_out    <<<BN/16,  256, 0, stream>>>(inx, ws, out);
}

// Round 13
// 319.178 us; speedup vs baseline: 3.7535x; 3.7535x over previous
//
#include <hip/hip_runtime.h>
#include <cfloat>

#define BN 16384   // B*N = 2*8192

// ---------------- workspace layout (float words) ----------------
#define WOFF_WT    0
#define WOFF_P1M   4096
#define WOFF_G1M   8192
#define WOFF_MMT   12288
#define WOFF_WD2T  16384
#define WOFF_G2T   20480
#define WOFF_WDN   24576
#define WOFF_WAL   28672
#define WOFF_WD1   32768
#define WOFF_BT    33024
#define WOFF_BAL   33088
#define WOFF_VC    33152
#define WOFF_UD1   33216
#define WOFF_UD2   33280
#define WOFF_UDN   33344
// bf16-packed (u32 pair) row-major weight copies for MFMA (filled by k0b)
#define WOFF_WMB   33792   // Wm  [c][cp] 2048 u32
#define WOFF_WD2B  35840   // Wd2s[c][cp] 2048 u32
#define WOFF_G2B   37888   // G2s [c][cp] 2048 u32
#define WB         39936

static constexpr size_t OFF_P1   = WB;                           // [BN][64]
static constexpr size_t OFF_G1   = OFF_P1 + (size_t)BN*64;       // [BN][64]
static constexpr size_t OFF_AL   = OFF_G1 + (size_t)BN*64;       // [BN][64]
static constexpr size_t OFF_R1   = OFF_AL + (size_t)BN*64;       // [BN][64]
static constexpr size_t OFF_P4   = OFF_R1 + (size_t)BN*64;       // [BN] float4 (x,y,z,sq)
static constexpr size_t OFF_IDX  = OFF_P4 + (size_t)BN*4;        // [BN][16] int
static constexpr size_t OFF_Y    = OFF_IDX + (size_t)BN*16;      // [BN][64]

struct P32 { const float* a[32]; };

#define WSWZ(i,o) ((o) ^ (((i)&7)<<2))

typedef __attribute__((ext_vector_type(8))) short bf16x8;
typedef __attribute__((ext_vector_type(4))) float f32x4;

__device__ __forceinline__ unsigned bf2(float lo, float hi) {
  unsigned a = __float_as_uint(lo); a = (a + 0x7fffu + ((a>>16)&1u)) >> 16;
  unsigned b = __float_as_uint(hi); b = (b + 0x7fffu + ((b>>16)&1u)) & 0xffff0000u;
  return a | b;
}

// =============== K0: fold weights ===============
__global__ __launch_bounds__(256) void k0_fold(P32 P, float* __restrict__ ws)
{
  const int bid = blockIdx.x, tid = threadIdx.x;
  const float* Wtop = P.a[2];  const float* btop = P.a[3];
  const float* stop = P.a[4];  const float* ttop = P.a[5];
  const float* Wphi = P.a[6];  const float* bphi = P.a[7];
  const float* Wpsi = P.a[8];  const float* bpsi = P.a[9];
  const float* Wal  = P.a[10]; const float* bal  = P.a[11];
  const float* Wg1  = P.a[12]; const float* bg1  = P.a[13];
  const float* sg1  = P.a[14]; const float* tg1  = P.a[15];
  const float* Wg2  = P.a[16];
  const float* sg2  = P.a[18];
  const float* Wd1  = P.a[20]; const float* bd1  = P.a[21];
  const float* sd1  = P.a[22]; const float* td1  = P.a[23];
  const float* Wd2  = P.a[24]; const float* bd2  = P.a[25];
  const float* sd2  = P.a[26]; const float* td2  = P.a[27];
  const float* Wdn  = P.a[28]; const float* bdn  = P.a[29];
  const float* sdn  = P.a[30]; const float* tdn  = P.a[31];

  if (bid == 0) {
    for (int e = tid; e < 4096; e += 256) { int o = e >> 6; ws[WOFF_WT + e] = stop[o]*Wtop[e]; }
    if (tid < 64) {
      ws[WOFF_BT  + tid] = stop[tid]*btop[tid] + ttop[tid];
      ws[WOFF_BAL + tid] = bal[tid];
      ws[WOFF_UD1 + tid] = sd1[tid]*bd1[tid] + td1[tid];
      ws[WOFF_UD2 + tid] = sd2[tid]*bd2[tid] + td2[tid];
      ws[WOFF_UDN + tid] = sdn[tid]*bdn[tid] + tdn[tid];
      float acc = 0.f;
      for (int c = 0; c < 64; ++c)
        acc += Wg1[tid*64+c] * (bphi[c] - bpsi[c] + sd2[c]*bd2[c] + td2[c]);
      ws[WOFF_VC + tid] = sg1[tid]*(acc + bg1[tid]) + tg1[tid];
    }
  } else if (bid == 1) {          // P1m[o][i] = s_g1[o] * (Wg1 Wphi)[o][i]
    for (int e = tid; e < 4096; e += 256) {
      int o = e >> 6, i = e & 63; float a = 0.f;
      for (int c = 0; c < 64; ++c) a += Wg1[o*64+c]*Wphi[c*64+i];
      ws[WOFF_P1M + e] = sg1[o]*a;
    }
  } else if (bid == 2) {          // G1m
    for (int e = tid; e < 4096; e += 256) {
      int o = e >> 6, i = e & 63; float a = 0.f;
      for (int c = 0; c < 64; ++c) a += Wg1[o*64+c]*Wpsi[c*64+i];
      ws[WOFF_G1M + e] = sg1[o]*a;
    }
  } else if (bid == 3) {          // MmT[cp][c] = s_g1[c] * (Wg1 diag(sd2) Wd2)[c][cp]
    for (int e = tid; e < 4096; e += 256) {
      int cp = e >> 6, c = e & 63; float a = 0.f;
      for (int u = 0; u < 64; ++u) a += Wg1[c*64+u]*sd2[u]*Wd2[u*64+cp];
      ws[WOFF_MMT + e] = sg1[c]*a;
    }
  } else if (bid == 4) {          // Wd2T[cp][c] ; Wd1f
    for (int e = tid; e < 4096; e += 256) {
      int cp = e >> 6, c = e & 63;
      ws[WOFF_WD2T + e] = sd2[c]*Wd2[c*64+cp];
    }
    if (tid < 192) ws[WOFF_WD1 + tid] = sd1[tid/3]*Wd1[tid];
  } else if (bid == 5) {          // G2T[cp][c]
    for (int e = tid; e < 4096; e += 256) {
      int cp = e >> 6, c = e & 63;
      ws[WOFF_G2T + e] = sg2[c]*Wg2[c*64+cp];
    }
  } else if (bid == 6) {          // Wdn row-major
    for (int e = tid; e < 4096; e += 256) { int o = e >> 6; ws[WOFF_WDN + e] = sdn[o]*Wdn[e]; }
  } else {                        // W_alpha copy
    for (int e = tid; e < 4096; e += 256) ws[WOFF_WAL + e] = Wal[e];
  }
}

// =============== K0b: pack MFMA weights to bf16 row-major [c][cp] ===============
__global__ __launch_bounds__(256) void k0b_pack(float* __restrict__ ws)
{
  const int m = blockIdx.x;                    // 0:Wm 1:Wd2s 2:G2s
  const int srcO = (m==0) ? WOFF_MMT : (m==1) ? WOFF_WD2T : WOFF_G2T;   // [cp][c] fp32
  const int dstO = (m==0) ? WOFF_WMB : (m==1) ? WOFF_WD2B : WOFF_G2B;   // [c][cp] bf16 pairs
  unsigned* dst = (unsigned*)&ws[dstO];
  for (int w = threadIdx.x; w < 2048; w += 256) {
    int c = w >> 5, pair = w & 31;
    float v0 = ws[srcO + (pair*2  )*64 + c];
    float v1 = ws[srcO + (pair*2+1)*64 + c];
    dst[w] = bf2(v0, v1);
  }
}

// =============== K1: per-point features (x -> P1,G1,AL) + r1 + p4 ===============
__global__ __launch_bounds__(256) void k1_feat(const float* __restrict__ inp,
                                               const float* __restrict__ inx,
                                               float* __restrict__ ws)
{
  __shared__ float tX[64][16];   // [c][pt]
  __shared__ float wT[64][64];   // transposed + swizzled weights
  const int tid = threadIdx.x;
  const int pt = tid & 15, q = tid >> 4;   // q in [0,16): channels q*4..q*4+3
  const int gid0 = blockIdx.x * 16;
  const int b = gid0 >> 13, n0 = gid0 & 8191;
  const size_t gq = (size_t)gid0 + pt;

  for (int r = tid; r < 1024; r += 256) {
    int c = r >> 4, col = r & 15;
    tX[c][col] = inx[((size_t)(b*64 + c) << 13) + n0 + col];
  }
  for (int r = tid; r < 4096; r += 256) {
    int o = r >> 6, i = r & 63;
    wT[i][WSWZ(i,o)] = ws[WOFF_WT + r];
  }
  __syncthreads();

  float acc[4];
  #pragma unroll
  for (int i = 0; i < 4; ++i) acc[i] = ws[WOFF_BT + q*4 + i];
  for (int ci = 0; ci < 64; ++ci) {
    float xv = tX[ci][pt];
    const float4 w4 = *(const float4*)&wT[ci][WSWZ(ci, q*4)];
    acc[0] = fmaf(w4.x, xv, acc[0]);
    acc[1] = fmaf(w4.y, xv, acc[1]);
    acc[2] = fmaf(w4.z, xv, acc[2]);
    acc[3] = fmaf(w4.w, xv, acc[3]);
  }
  __syncthreads();
  #pragma unroll
  for (int i = 0; i < 4; ++i) tX[q*4 + i][pt] = acc[i];

  // p4 + r1 (global only)
  {
    size_t pb = (size_t)b*3*8192 + n0 + pt;
    float px = inp[pb], py = inp[pb + 8192], pz = inp[pb + 16384];
    float sq = __fadd_rn(__fadd_rn(__fmul_rn(px,px), __fmul_rn(py,py)), __fmul_rn(pz,pz));
    if (q == 0) *(float4*)&ws[OFF_P4 + gq*4] = make_float4(px,py,pz,sq);
    float r1v[4];
    #pragma unroll
    for (int i = 0; i < 4; ++i) {
      int c = q*4 + i;
      float a = ws[WOFF_WD1 + c*3+0]*px;
      a = fmaf(ws[WOFF_WD1 + c*3+1], py, a);
      a = fmaf(ws[WOFF_WD1 + c*3+2], pz, a);
      r1v[i] = a;
    }
    *(float4*)&ws[OFF_R1 + gq*64 + q*4] = make_float4(r1v[0], r1v[1], r1v[2], r1v[3]);
  }
  __syncthreads();

  #pragma unroll
  for (int m = 0; m < 3; ++m) {
    const int    mof = (m==0) ? WOFF_P1M : (m==1) ? WOFF_G1M : WOFF_WAL;
    const size_t oof = (m==0) ? OFF_P1   : (m==1) ? OFF_G1   : OFF_AL;
    __syncthreads();
    for (int r = tid; r < 4096; r += 256) {
      int o = r >> 6, i = r & 63;
      wT[i][WSWZ(i,o)] = ws[mof + r];
    }
    __syncthreads();
    #pragma unroll
    for (int i = 0; i < 4; ++i) acc[i] = (m == 2) ? ws[WOFF_BAL + q*4 + i] : 0.f;
    for (int ci = 0; ci < 64; ++ci) {
      float xv = tX[ci][pt];
      const float4 w4 = *(const float4*)&wT[ci][WSWZ(ci, q*4)];
      acc[0] = fmaf(w4.x, xv, acc[0]);
      acc[1] = fmaf(w4.y, xv, acc[1]);
      acc[2] = fmaf(w4.z, xv, acc[2]);
      acc[3] = fmaf(w4.w, xv, acc[3]);
    }
    *(float4*)&ws[oof + gq*64 + q*4] = make_float4(acc[0], acc[1], acc[2], acc[3]);
  }
}

// numpy-exact distance
__device__ __forceinline__ float pdist(const float4 q4, const float4 c4) {
  float m = __fadd_rn(__fadd_rn(__fmul_rn(q4.x,c4.x), __fmul_rn(q4.y,c4.y)), __fmul_rn(q4.z,c4.z));
  return __fsub_rn(__fadd_rn(q4.w, c4.w), __fmul_rn(2.f, m));
}

__device__ __forceinline__ unsigned dmono(float d) {
  unsigned db = __float_as_uint(d);
  return db ^ (((int)db < 0) ? 0xffffffffu : 0x80000000u);
}

// branchless sorted insert into 5-slot ascending register list (u64 keys)
__device__ __forceinline__ void ins5(unsigned long long& k0, unsigned long long& k1,
                                     unsigned long long& k2, unsigned long long& k3,
                                     unsigned long long& k4, unsigned long long x)
{
  unsigned long long t;
  t = (k0 < x) ? k0 : x;  x = (k0 < x) ? x : k0;  k0 = t;
  t = (k1 < x) ? k1 : x;  x = (k1 < x) ? x : k1;  k1 = t;
  t = (k2 < x) ? k2 : x;  x = (k2 < x) ? x : k2;  k2 = t;
  t = (k3 < x) ? k3 : x;  x = (k3 < x) ? x : k3;  k3 = t;
  k4 = (k4 < x) ? k4 : x;
}

// =============== K2: exact top-16 KNN, single pass (wave-per-query) ===============
// R11-proven form (196 us, VALUBusy 94%). Each lane keeps its exact top-5 u64 keys
// (dmono(d)<<32 | idx) via branchless bubble insert; 320-key union reduced by 16
// wave-argmin rounds. Soundness: if all lanes' saved k4 >= m16 the union provably
// contains the true top-16 (P(violation) ~ 2.6e-4/query, empirically 0 on this input);
// else guaranteed serial rescan.
__global__ __launch_bounds__(256) void k2_topk(float* __restrict__ ws)
{
  __shared__ float4 tile[1024];   // 16 KB
  const int tid = threadIdx.x;
  const int lane = tid & 63, w = tid >> 6;
  const int gid = blockIdx.x*4 + w;
  const int b = gid >> 13;
  const float4 q4 = *(const float4*)&ws[OFF_P4 + (size_t)gid*4];
  const float4* cp4 = (const float4*)&ws[OFF_P4 + (size_t)b*8192*4];
  int* ib = (int*)&ws[OFF_IDX];

  unsigned long long k0=~0ull, k1=~0ull, k2=~0ull, k3=~0ull, k4=~0ull;

  #pragma unroll 1
  for (int c0 = 0; c0 < 8192; c0 += 1024) {
    __syncthreads();
    #pragma unroll
    for (int t = 0; t < 4; ++t) tile[tid + t*256] = cp4[c0 + tid + t*256];
    __syncthreads();
    #pragma unroll 1
    for (int r = 0; r < 16; ++r) {
      const int ci = r*64 + lane;
      float d = pdist(q4, tile[ci]);
      unsigned long long x = ((unsigned long long)dmono(d) << 32) | (unsigned)(c0 + ci);
      ins5(k0, k1, k2, k3, k4, x);
    }
  }

  const unsigned long long savedk4 = k4;

  // 16 wave-argmin rounds over the 320-key union (5 keys/lane)
  unsigned myres = 0u;
  unsigned long long m = 0ull;
  #pragma unroll 1
  for (int r = 0; r < 16; ++r) {
    unsigned long long a01 = (k0 < k1) ? k0 : k1;
    unsigned long long a23 = (k2 < k3) ? k2 : k3;
    unsigned long long a03 = (a01 < a23) ? a01 : a23;
    m = (a03 < k4) ? a03 : k4;
    #pragma unroll
    for (int s = 1; s < 64; s <<= 1) {
      unsigned long long o = __shfl_xor(m, s);
      m = (o < m) ? o : m;
    }
    k0 = (k0 == m) ? ~0ull : k0;  k1 = (k1 == m) ? ~0ull : k1;
    k2 = (k2 == m) ? ~0ull : k2;  k3 = (k3 == m) ? ~0ull : k3;
    k4 = (k4 == m) ? ~0ull : k4;
    if (lane == r) myres = (unsigned)(m & 0xffffffffu);
  }

  // safety check: m (last round) is the 16th-smallest of the union
  const bool unsafe = __ballot(savedk4 < m) != 0ull;
  if (!unsafe) {
    if (lane < 16) ib[(size_t)gid*16 + lane] = (int)myres;
  } else {
    // guaranteed-correct fallback (~2.6e-4 per query): serial rescan
    if (lane == 0) {
      float ds[16]; int is[16];
      #pragma unroll
      for (int r = 0; r < 16; ++r) { ds[r] = FLT_MAX; is[r] = 0x7fffffff; }
      for (int t = 0; t < 8192; ++t) {
        float d = pdist(q4, cp4[t]);
        if (d < ds[15]) {
          #pragma unroll
          for (int s = 15; s >= 0; --s) {
            bool bs = d < ds[s];
            bool bm = (s > 0) ? (d < ds[s-1]) : false;
            float dn = bs ? (bm ? ds[s-1] : d) : ds[s];
            int   jn = bs ? (bm ? is[s-1] : t) : is[s];
            ds[s] = dn; is[s] = jn;
          }
        }
      }
      #pragma unroll
      for (int r = 0; r < 16; ++r) ib[(size_t)gid*16 + r] = is[r];
    }
  }
}

// =============== K3 (MFMA): fused per-point block (weights in LDS) ===============
// 8 points/block: hL 16 KB, total LDS 40 KB -> 4 blocks/CU for the
// gather-latency-bound phase. Arithmetic identical per point (bit-for-bit).
__global__ __launch_bounds__(256) void k3_mfma(float* __restrict__ ws, float* __restrict__ out)
{
  __shared__ __align__(16) unsigned char wL[24576];  // 3 x [64 c][64 cp] bf16, swizzled
  __shared__ __align__(16) unsigned char hL[16384];  // [128 col][64 cp] bf16, swizzled
  const int tid = threadIdx.x;
  const int lane = tid & 63, wid = tid >> 6;
  const int l15 = lane & 15, hi = lane >> 4;
  const int gid0 = blockIdx.x * 8;        // first global point of block
  const int b = gid0 >> 13;
  const int n0 = gid0 & 8191;

  // ---- stage bf16 weights into LDS (swizzled rows) ----
  {
    const uint4* wsrc = (const uint4*)&ws[WOFF_WMB];
    for (int t = tid; t < 1536; t += 256) {
      int m = t >> 9, r = t & 511;
      int c = r >> 3, q = r & 7;
      uint4 v = wsrc[t];
      *(uint4*)(wL + m*8192 + ((c*128 + q*16) ^ ((c&7)<<4))) = v;
    }
  }
  // ---- compute h for own column (col = tid, first 128 threads) ----
  if (tid < 128) {
    const int pt = tid >> 4, kq = tid & 15;
    const size_t gq = (size_t)gid0 + pt;
    const int jh = ((const int*)&ws[OFF_IDX])[gq*16 + kq];
    const size_t gjh = (size_t)b*8192 + jh;
    const float4* Ar = (const float4*)&ws[OFF_R1 + gq*64];
    const float4* Br = (const float4*)&ws[OFF_R1 + gjh*64];
    const float4* Ur = (const float4*)&ws[WOFF_UD1];
    const int swzh = (tid & 7) << 4;
    #pragma unroll
    for (int t = 0; t < 16; ++t) {
      float4 a = Ar[t], bb = Br[t], u = Ur[t];
      float v0 = fmaxf(a.x - bb.x + u.x, 0.f);
      float v1 = fmaxf(a.y - bb.y + u.y, 0.f);
      float v2 = fmaxf(a.z - bb.z + u.z, 0.f);
      float v3 = fmaxf(a.w - bb.w + u.w, 0.f);
      *(uint2*)(hL + ((tid*128 + t*8) ^ swzh)) = make_uint2(bf2(v0,v1), bf2(v2,v3));
    }
  }
  __syncthreads();

  float* attnp = out + (size_t)2*64*8192;   // attn region after out0
  const f32x4 zf = {0.f, 0.f, 0.f, 0.f};

  #pragma unroll 1
  for (int i = 0; i < 2; ++i) {
    const int ct = (wid << 1) + i;          // coltile == point index in block (0..7)
    const int n = n0 + ct;
    const size_t gqc = (size_t)gid0 + ct;
    const int mycol = (ct << 4) + l15;      // 0..127
    const int swz = (mycol & 7) << 4;
    const int hbase = mycol*128 + hi*16;
    bf16x8 hb0 = *(const bf16x8*)(hL + ((hbase     ) ^ swz));
    bf16x8 hb1 = *(const bf16x8*)(hL + ((hbase + 64) ^ swz));
    const int jj = ((const int*)&ws[OFF_IDX])[gqc*16 + l15];
    const size_t gjc = (size_t)b*8192 + jj;

    // ---- D-GEMM (pos) + M-GEMM ----
    f32x4 accD[4], accM[4];
    #pragma unroll
    for (int rt = 0; rt < 4; ++rt) { accD[rt] = zf; accM[rt] = zf; }
    #pragma unroll
    for (int rt = 0; rt < 4; ++rt) {
      const int c = (rt << 4) + l15;
      const int ws2 = (c & 7) << 4;
      const int wb = c*128 + hi*16;
      bf16x8 m0 = *(const bf16x8*)(wL + (((wb     ) ^ ws2)));
      bf16x8 m1 = *(const bf16x8*)(wL + (((wb + 64) ^ ws2)));
      bf16x8 d0 = *(const bf16x8*)(wL + (8192 + ((wb     ) ^ ws2)));
      bf16x8 d1 = *(const bf16x8*)(wL + (8192 + ((wb + 64) ^ ws2)));
      accM[rt] = __builtin_amdgcn_mfma_f32_16x16x32_bf16(m0, hb0, accM[rt], 0, 0, 0);
      accM[rt] = __builtin_amdgcn_mfma_f32_16x16x32_bf16(m1, hb1, accM[rt], 0, 0, 0);
      accD[rt] = __builtin_amdgcn_mfma_f32_16x16x32_bf16(d0, hb0, accD[rt], 0, 0, 0);
      accD[rt] = __builtin_amdgcn_mfma_f32_16x16x32_bf16(d1, hb1, accD[rt], 0, 0, 0);
    }

    // ---- hg = relu(aM + P1[n] - G1[j] + vc), write bf16 back into hL (in place) ----
    #pragma unroll
    for (int rt = 0; rt < 4; ++rt) {
      const int c0 = (rt << 4) + (hi << 2);
      const float4 p1 = *(const float4*)&ws[OFF_P1 + gqc*64 + c0];
      const float4 g1 = *(const float4*)&ws[OFF_G1 + gjc*64 + c0];
      const float4 vc = *(const float4*)&ws[WOFF_VC + c0];
      float h0 = fmaxf(accM[rt][0] + p1.x - g1.x + vc.x, 0.f);
      float h1 = fmaxf(accM[rt][1] + p1.y - g1.y + vc.y, 0.f);
      float h2 = fmaxf(accM[rt][2] + p1.z - g1.z + vc.z, 0.f);
      float h3 = fmaxf(accM[rt][3] + p1.w - g1.w + vc.w, 0.f);
      *(uint2*)(hL + ((mycol*128 + (c0 << 1)) ^ swz)) = make_uint2(bf2(h0,h1), bf2(h2,h3));
    }

    // ---- G2-GEMM on hg (wave-local; DS ops are in-order within a wave) ----
    bf16x8 gb0 = *(const bf16x8*)(hL + ((hbase     ) ^ swz));
    bf16x8 gb1 = *(const bf16x8*)(hL + ((hbase + 64) ^ swz));
    f32x4 accG[4];
    #pragma unroll
    for (int rt = 0; rt < 4; ++rt) accG[rt] = zf;
    #pragma unroll
    for (int rt = 0; rt < 4; ++rt) {
      const int c = (rt << 4) + l15;
      const int ws2 = (c & 7) << 4;
      const int wb = c*128 + hi*16;
      bf16x8 g0 = *(const bf16x8*)(wL + (16384 + ((wb     ) ^ ws2)));
      bf16x8 g1f = *(const bf16x8*)(wL + (16384 + ((wb + 64) ^ ws2)));
      accG[rt] = __builtin_amdgcn_mfma_f32_16x16x32_bf16(g0,  gb0, accG[rt], 0, 0, 0);
      accG[rt] = __builtin_amdgcn_mfma_f32_16x16x32_bf16(g1f, gb1, accG[rt], 0, 0, 0);
    }

    // ---- softmax over kk (lane&15), attn store, y reduce ----
    #pragma unroll
    for (int rt = 0; rt < 4; ++rt) {
      const int c0 = (rt << 4) + (hi << 2);
      const float4 al = *(const float4*)&ws[OFF_AL + gjc*64 + c0];
      const float4 u2 = *(const float4*)&ws[WOFF_UD2 + c0];
      float y4[4];
      #pragma unroll
      for (int r = 0; r < 4; ++r) {
        float g = accG[rt][r];
        float mx = g;
        mx = fmaxf(mx, __shfl_xor(mx, 1));
        mx = fmaxf(mx, __shfl_xor(mx, 2));
        mx = fmaxf(mx, __shfl_xor(mx, 4));
        mx = fmaxf(mx, __shfl_xor(mx, 8));
        float e = __expf(g - mx);
        float sm = e;
        sm += __shfl_xor(sm, 1);
        sm += __shfl_xor(sm, 2);
        sm += __shfl_xor(sm, 4);
        sm += __shfl_xor(sm, 8);
        float rs;
        asm("v_rcp_f32 %0, %1" : "=v"(rs) : "v"(sm));
        float a = e * rs;
        attnp[(((size_t)(b*64 + c0 + r) << 13) + n)*16 + l15] = a;
        float pv = ((const float*)&al)[r] + accD[rt][r] + ((const float*)&u2)[r];
        float yv = a * pv;
        yv += __shfl_xor(yv, 1);
        yv += __shfl_xor(yv, 2);
        yv += __shfl_xor(yv, 4);
        yv += __shfl_xor(yv, 8);
        y4[r] = yv;
      }
      if (l15 == 0)
        *(float4*)&ws[OFF_Y + gqc*64 + c0] = make_float4(y4[0], y4[1], y4[2], y4[3]);
    }
  }
}

// =============== K4: out = Wdn*y + udn + input_x ===============
__global__ __launch_bounds__(256) void k4_out(const float* __restrict__ inx,
                                              float* __restrict__ ws,
                                              float* __restrict__ out)
{
  __shared__ float yS[16][64];
  __shared__ float wT[64][64];
  const int tid = threadIdx.x;
  const int pt = tid & 15, q = tid >> 4;   // channels q*4..q*4+3
  const int gid0 = blockIdx.x*16;
  const int b = gid0 >> 13, n0 = gid0 & 8191;
  for (int r = tid; r < 1024; r += 256) {
    int p2 = r >> 6, c = r & 63;
    yS[p2][c ^ p2] = ws[OFF_Y + (size_t)(gid0 + p2)*64 + c];
  }
  for (int r = tid; r < 4096; r += 256) {
    int o = r >> 6, i = r & 63;
    wT[i][WSWZ(i,o)] = ws[WOFF_WDN + r];
  }
  __syncthreads();
  float acc[4];
  #pragma unroll
  for (int i = 0; i < 4; ++i) acc[i] = ws[WOFF_UDN + q*4 + i];
  for (int ci = 0; ci < 64; ++ci) {
    float yv = yS[pt][ci ^ pt];
    const float4 w4 = *(const float4*)&wT[ci][WSWZ(ci, q*4)];
    acc[0] = fmaf(w4.x, yv, acc[0]);
    acc[1] = fmaf(w4.y, yv, acc[1]);
    acc[2] = fmaf(w4.z, yv, acc[2]);
    acc[3] = fmaf(w4.w, yv, acc[3]);
  }
  #pragma unroll
  for (int i = 0; i < 4; ++i) {
    const int c = q*4 + i;
    size_t o = ((size_t)(b*64 + c) << 13) + n0 + pt;
    out[o] = acc[i] + inx[o];
  }
}

extern "C" void kernel_launch(void* const* d_in, const int* in_sizes, int n_in,
                              void* d_out, int out_size, void* d_ws, size_t ws_size,
                              hipStream_t stream)
{
  (void)in_sizes; (void)n_in; (void)out_size; (void)ws_size;
  float* ws = (float*)d_ws;
  const float* inp = (const float*)d_in[0];
  const float* inx = (const float*)d_in[1];
  float* out = (float*)d_out;
  P32 P;
  for (int i = 0; i < 32; ++i) P.a[i] = (const float*)d_in[i];

  k0_fold   <<<8,      256, 0, stream>>>(P, ws);
  k0b_pack  <<<3,      256, 0, stream>>>(ws);
  k1_feat   <<<BN/16,  256, 0, stream>>>(inp, inx, ws);
  k2_topk   <<<BN/4,   256, 0, stream>>>(ws);
  k3_mfma   <<<BN/8,   256, 0, stream>>>(ws, out);
  k4_out    <<<BN/16,  256, 0, stream>>>(inx, ws, out);
}

// Round 14
// 293.244 us; speedup vs baseline: 4.0855x; 1.0884x over previous
//
#include <hip/hip_runtime.h>
#include <cfloat>

#define BN 16384   // B*N = 2*8192

// ---------------- workspace layout (float words) ----------------
#define WOFF_WT    0
#define WOFF_P1M   4096
#define WOFF_G1M   8192
#define WOFF_MMT   12288
#define WOFF_WD2T  16384
#define WOFF_G2T   20480
#define WOFF_WDN   24576
#define WOFF_WAL   28672
#define WOFF_WD1   32768
#define WOFF_BT    33024
#define WOFF_BAL   33088
#define WOFF_VC    33152
#define WOFF_UD1   33216
#define WOFF_UD2   33280
#define WOFF_UDN   33344
// bf16-packed (u32 pair) row-major weight copies for MFMA (filled by k0b)
#define WOFF_WMB   33792   // Wm  [c][cp] 2048 u32
#define WOFF_WD2B  35840   // Wd2s[c][cp] 2048 u32
#define WOFF_G2B   37888   // G2s [c][cp] 2048 u32
#define WB         39936

static constexpr size_t OFF_P1   = WB;                           // [BN][64]
static constexpr size_t OFF_G1   = OFF_P1 + (size_t)BN*64;       // [BN][64]
static constexpr size_t OFF_AL   = OFF_G1 + (size_t)BN*64;       // [BN][64]
static constexpr size_t OFF_R1   = OFF_AL + (size_t)BN*64;       // [BN][64]
static constexpr size_t OFF_P4   = OFF_R1 + (size_t)BN*64;       // [BN] float4 (x,y,z,sq)
static constexpr size_t OFF_IDX  = OFF_P4 + (size_t)BN*4;        // [BN][16] int
static constexpr size_t OFF_Y    = OFF_IDX + (size_t)BN*16;      // [BN][64]

struct P32 { const float* a[32]; };

#define WSWZ(i,o) ((o) ^ (((i)&7)<<2))

typedef __attribute__((ext_vector_type(8))) short bf16x8;
typedef __attribute__((ext_vector_type(4))) float f32x4;

__device__ __forceinline__ unsigned bf2(float lo, float hi) {
  unsigned a = __float_as_uint(lo); a = (a + 0x7fffu + ((a>>16)&1u)) >> 16;
  unsigned b = __float_as_uint(hi); b = (b + 0x7fffu + ((b>>16)&1u)) & 0xffff0000u;
  return a | b;
}

// =============== K0: fold weights ===============
__global__ __launch_bounds__(256) void k0_fold(P32 P, float* __restrict__ ws)
{
  const int bid = blockIdx.x, tid = threadIdx.x;
  const float* Wtop = P.a[2];  const float* btop = P.a[3];
  const float* stop = P.a[4];  const float* ttop = P.a[5];
  const float* Wphi = P.a[6];  const float* bphi = P.a[7];
  const float* Wpsi = P.a[8];  const float* bpsi = P.a[9];
  const float* Wal  = P.a[10]; const float* bal  = P.a[11];
  const float* Wg1  = P.a[12]; const float* bg1  = P.a[13];
  const float* sg1  = P.a[14]; const float* tg1  = P.a[15];
  const float* Wg2  = P.a[16];
  const float* sg2  = P.a[18];
  const float* Wd1  = P.a[20]; const float* bd1  = P.a[21];
  const float* sd1  = P.a[22]; const float* td1  = P.a[23];
  const float* Wd2  = P.a[24]; const float* bd2  = P.a[25];
  const float* sd2  = P.a[26]; const float* td2  = P.a[27];
  const float* Wdn  = P.a[28]; const float* bdn  = P.a[29];
  const float* sdn  = P.a[30]; const float* tdn  = P.a[31];

  if (bid == 0) {
    for (int e = tid; e < 4096; e += 256) { int o = e >> 6; ws[WOFF_WT + e] = stop[o]*Wtop[e]; }
    if (tid < 64) {
      ws[WOFF_BT  + tid] = stop[tid]*btop[tid] + ttop[tid];
      ws[WOFF_BAL + tid] = bal[tid];
      ws[WOFF_UD1 + tid] = sd1[tid]*bd1[tid] + td1[tid];
      ws[WOFF_UD2 + tid] = sd2[tid]*bd2[tid] + td2[tid];
      ws[WOFF_UDN + tid] = sdn[tid]*bdn[tid] + tdn[tid];
      float acc = 0.f;
      for (int c = 0; c < 64; ++c)
        acc += Wg1[tid*64+c] * (bphi[c] - bpsi[c] + sd2[c]*bd2[c] + td2[c]);
      ws[WOFF_VC + tid] = sg1[tid]*(acc + bg1[tid]) + tg1[tid];
    }
  } else if (bid == 1) {          // P1m[o][i] = s_g1[o] * (Wg1 Wphi)[o][i]
    for (int e = tid; e < 4096; e += 256) {
      int o = e >> 6, i = e & 63; float a = 0.f;
      for (int c = 0; c < 64; ++c) a += Wg1[o*64+c]*Wphi[c*64+i];
      ws[WOFF_P1M + e] = sg1[o]*a;
    }
  } else if (bid == 2) {          // G1m
    for (int e = tid; e < 4096; e += 256) {
      int o = e >> 6, i = e & 63; float a = 0.f;
      for (int c = 0; c < 64; ++c) a += Wg1[o*64+c]*Wpsi[c*64+i];
      ws[WOFF_G1M + e] = sg1[o]*a;
    }
  } else if (bid == 3) {          // MmT[cp][c] = s_g1[c] * (Wg1 diag(sd2) Wd2)[c][cp]
    for (int e = tid; e < 4096; e += 256) {
      int cp = e >> 6, c = e & 63; float a = 0.f;
      for (int u = 0; u < 64; ++u) a += Wg1[c*64+u]*sd2[u]*Wd2[u*64+cp];
      ws[WOFF_MMT + e] = sg1[c]*a;
    }
  } else if (bid == 4) {          // Wd2T[cp][c] ; Wd1f
    for (int e = tid; e < 4096; e += 256) {
      int cp = e >> 6, c = e & 63;
      ws[WOFF_WD2T + e] = sd2[c]*Wd2[c*64+cp];
    }
    if (tid < 192) ws[WOFF_WD1 + tid] = sd1[tid/3]*Wd1[tid];
  } else if (bid == 5) {          // G2T[cp][c]
    for (int e = tid; e < 4096; e += 256) {
      int cp = e >> 6, c = e & 63;
      ws[WOFF_G2T + e] = sg2[c]*Wg2[c*64+cp];
    }
  } else if (bid == 6) {          // Wdn row-major
    for (int e = tid; e < 4096; e += 256) { int o = e >> 6; ws[WOFF_WDN + e] = sdn[o]*Wdn[e]; }
  } else {                        // W_alpha copy
    for (int e = tid; e < 4096; e += 256) ws[WOFF_WAL + e] = Wal[e];
  }
}

// =============== K0b: pack MFMA weights to bf16 row-major [c][cp] ===============
__global__ __launch_bounds__(256) void k0b_pack(float* __restrict__ ws)
{
  const int m = blockIdx.x;                    // 0:Wm 1:Wd2s 2:G2s
  const int srcO = (m==0) ? WOFF_MMT : (m==1) ? WOFF_WD2T : WOFF_G2T;   // [cp][c] fp32
  const int dstO = (m==0) ? WOFF_WMB : (m==1) ? WOFF_WD2B : WOFF_G2B;   // [c][cp] bf16 pairs
  unsigned* dst = (unsigned*)&ws[dstO];
  for (int w = threadIdx.x; w < 2048; w += 256) {
    int c = w >> 5, pair = w & 31;
    float v0 = ws[srcO + (pair*2  )*64 + c];
    float v1 = ws[srcO + (pair*2+1)*64 + c];
    dst[w] = bf2(v0, v1);
  }
}

// =============== K1: per-point features (x -> P1,G1,AL) + r1 + p4 ===============
__global__ __launch_bounds__(256) void k1_feat(const float* __restrict__ inp,
                                               const float* __restrict__ inx,
                                               float* __restrict__ ws)
{
  __shared__ float tX[64][16];   // [c][pt]
  __shared__ float wT[64][64];   // transposed + swizzled weights
  const int tid = threadIdx.x;
  const int pt = tid & 15, q = tid >> 4;   // q in [0,16): channels q*4..q*4+3
  const int gid0 = blockIdx.x * 16;
  const int b = gid0 >> 13, n0 = gid0 & 8191;
  const size_t gq = (size_t)gid0 + pt;

  for (int r = tid; r < 1024; r += 256) {
    int c = r >> 4, col = r & 15;
    tX[c][col] = inx[((size_t)(b*64 + c) << 13) + n0 + col];
  }
  for (int r = tid; r < 4096; r += 256) {
    int o = r >> 6, i = r & 63;
    wT[i][WSWZ(i,o)] = ws[WOFF_WT + r];
  }
  __syncthreads();

  float acc[4];
  #pragma unroll
  for (int i = 0; i < 4; ++i) acc[i] = ws[WOFF_BT + q*4 + i];
  for (int ci = 0; ci < 64; ++ci) {
    float xv = tX[ci][pt];
    const float4 w4 = *(const float4*)&wT[ci][WSWZ(ci, q*4)];
    acc[0] = fmaf(w4.x, xv, acc[0]);
    acc[1] = fmaf(w4.y, xv, acc[1]);
    acc[2] = fmaf(w4.z, xv, acc[2]);
    acc[3] = fmaf(w4.w, xv, acc[3]);
  }
  __syncthreads();
  #pragma unroll
  for (int i = 0; i < 4; ++i) tX[q*4 + i][pt] = acc[i];

  // p4 + r1 (global only)
  {
    size_t pb = (size_t)b*3*8192 + n0 + pt;
    float px = inp[pb], py = inp[pb + 8192], pz = inp[pb + 16384];
    float sq = __fadd_rn(__fadd_rn(__fmul_rn(px,px), __fmul_rn(py,py)), __fmul_rn(pz,pz));
    if (q == 0) *(float4*)&ws[OFF_P4 + gq*4] = make_float4(px,py,pz,sq);
    float r1v[4];
    #pragma unroll
    for (int i = 0; i < 4; ++i) {
      int c = q*4 + i;
      float a = ws[WOFF_WD1 + c*3+0]*px;
      a = fmaf(ws[WOFF_WD1 + c*3+1], py, a);
      a = fmaf(ws[WOFF_WD1 + c*3+2], pz, a);
      r1v[i] = a;
    }
    *(float4*)&ws[OFF_R1 + gq*64 + q*4] = make_float4(r1v[0], r1v[1], r1v[2], r1v[3]);
  }
  __syncthreads();

  #pragma unroll
  for (int m = 0; m < 3; ++m) {
    const int    mof = (m==0) ? WOFF_P1M : (m==1) ? WOFF_G1M : WOFF_WAL;
    const size_t oof = (m==0) ? OFF_P1   : (m==1) ? OFF_G1   : OFF_AL;
    __syncthreads();
    for (int r = tid; r < 4096; r += 256) {
      int o = r >> 6, i = r & 63;
      wT[i][WSWZ(i,o)] = ws[mof + r];
    }
    __syncthreads();
    #pragma unroll
    for (int i = 0; i < 4; ++i) acc[i] = (m == 2) ? ws[WOFF_BAL + q*4 + i] : 0.f;
    for (int ci = 0; ci < 64; ++ci) {
      float xv = tX[ci][pt];
      const float4 w4 = *(const float4*)&wT[ci][WSWZ(ci, q*4)];
      acc[0] = fmaf(w4.x, xv, acc[0]);
      acc[1] = fmaf(w4.y, xv, acc[1]);
      acc[2] = fmaf(w4.z, xv, acc[2]);
      acc[3] = fmaf(w4.w, xv, acc[3]);
    }
    *(float4*)&ws[oof + gq*64 + q*4] = make_float4(acc[0], acc[1], acc[2], acc[3]);
  }
}

// numpy-exact distance
__device__ __forceinline__ float pdist(const float4 q4, const float4 c4) {
  float m = __fadd_rn(__fadd_rn(__fmul_rn(q4.x,c4.x), __fmul_rn(q4.y,c4.y)), __fmul_rn(q4.z,c4.z));
  return __fsub_rn(__fadd_rn(q4.w, c4.w), __fmul_rn(2.f, m));
}

__device__ __forceinline__ unsigned dmono(float d) {
  unsigned db = __float_as_uint(d);
  return db ^ (((int)db < 0) ? 0xffffffffu : 0x80000000u);
}

// branchless sorted insert into 5-slot ascending register list (u64 keys)
__device__ __forceinline__ void ins5(unsigned long long& k0, unsigned long long& k1,
                                     unsigned long long& k2, unsigned long long& k3,
                                     unsigned long long& k4, unsigned long long x)
{
  unsigned long long t;
  t = (k0 < x) ? k0 : x;  x = (k0 < x) ? x : k0;  k0 = t;
  t = (k1 < x) ? k1 : x;  x = (k1 < x) ? x : k1;  k1 = t;
  t = (k2 < x) ? k2 : x;  x = (k2 < x) ? x : k2;  k2 = t;
  t = (k3 < x) ? k3 : x;  x = (k3 < x) ? x : k3;  k3 = t;
  k4 = (k4 < x) ? k4 : x;
}

// =============== K2: exact top-16 KNN, single pass (wave-per-query) ===============
// R11-proven form. Each lane keeps its exact top-5 u64 keys (dmono(d)<<32 | idx) via
// branchless bubble insert; 320-key union reduced by 16 wave-argmin rounds.
// Scan loop unrolled x4: amortizes loop/address overhead and overlaps 4 independent
// pdist/key computations with the serial ladder chain (same insertion order -> bit-identical).
// Soundness: if all lanes' saved k4 >= m16 the union provably contains the true top-16;
// else guaranteed serial rescan (P ~ 2.6e-4/query, empirically 0 on this input).
__global__ __launch_bounds__(256) void k2_topk(float* __restrict__ ws)
{
  __shared__ float4 tile[1024];   // 16 KB
  const int tid = threadIdx.x;
  const int lane = tid & 63, w = tid >> 6;
  const int gid = blockIdx.x*4 + w;
  const int b = gid >> 13;
  const float4 q4 = *(const float4*)&ws[OFF_P4 + (size_t)gid*4];
  const float4* cp4 = (const float4*)&ws[OFF_P4 + (size_t)b*8192*4];
  int* ib = (int*)&ws[OFF_IDX];

  unsigned long long k0=~0ull, k1=~0ull, k2=~0ull, k3=~0ull, k4=~0ull;

  #pragma unroll 1
  for (int c0 = 0; c0 < 8192; c0 += 1024) {
    __syncthreads();
    #pragma unroll
    for (int t = 0; t < 4; ++t) tile[tid + t*256] = cp4[c0 + tid + t*256];
    __syncthreads();
    #pragma unroll 4
    for (int r = 0; r < 16; ++r) {
      const int ci = r*64 + lane;
      float d = pdist(q4, tile[ci]);
      unsigned long long x = ((unsigned long long)dmono(d) << 32) | (unsigned)(c0 + ci);
      ins5(k0, k1, k2, k3, k4, x);
    }
  }

  const unsigned long long savedk4 = k4;

  // 16 wave-argmin rounds over the 320-key union (5 keys/lane)
  unsigned myres = 0u;
  unsigned long long m = 0ull;
  #pragma unroll 1
  for (int r = 0; r < 16; ++r) {
    unsigned long long a01 = (k0 < k1) ? k0 : k1;
    unsigned long long a23 = (k2 < k3) ? k2 : k3;
    unsigned long long a03 = (a01 < a23) ? a01 : a23;
    m = (a03 < k4) ? a03 : k4;
    #pragma unroll
    for (int s = 1; s < 64; s <<= 1) {
      unsigned long long o = __shfl_xor(m, s);
      m = (o < m) ? o : m;
    }
    k0 = (k0 == m) ? ~0ull : k0;  k1 = (k1 == m) ? ~0ull : k1;
    k2 = (k2 == m) ? ~0ull : k2;  k3 = (k3 == m) ? ~0ull : k3;
    k4 = (k4 == m) ? ~0ull : k4;
    if (lane == r) myres = (unsigned)(m & 0xffffffffu);
  }

  // safety check: m (last round) is the 16th-smallest of the union
  const bool unsafe = __ballot(savedk4 < m) != 0ull;
  if (!unsafe) {
    if (lane < 16) ib[(size_t)gid*16 + lane] = (int)myres;
  } else {
    // guaranteed-correct fallback (~2.6e-4 per query): serial rescan
    if (lane == 0) {
      float ds[16]; int is[16];
      #pragma unroll
      for (int r = 0; r < 16; ++r) { ds[r] = FLT_MAX; is[r] = 0x7fffffff; }
      for (int t = 0; t < 8192; ++t) {
        float d = pdist(q4, cp4[t]);
        if (d < ds[15]) {
          #pragma unroll
          for (int s = 15; s >= 0; --s) {
            bool bs = d < ds[s];
            bool bm = (s > 0) ? (d < ds[s-1]) : false;
            float dn = bs ? (bm ? ds[s-1] : d) : ds[s];
            int   jn = bs ? (bm ? is[s-1] : t) : is[s];
            ds[s] = dn; is[s] = jn;
          }
        }
      }
      #pragma unroll
      for (int r = 0; r < 16; ++r) ib[(size_t)gid*16 + r] = is[r];
    }
  }
}

// =============== K3 (MFMA): fused per-point block (weights in LDS, 16 pts/block) ===============
__global__ __launch_bounds__(256) void k3_mfma(float* __restrict__ ws, float* __restrict__ out)
{
  __shared__ __align__(16) unsigned char wL[24576];  // 3 x [64 c][64 cp] bf16, swizzled
  __shared__ __align__(16) unsigned char hL[32768];  // [256 col][64 cp] bf16, swizzled
  const int tid = threadIdx.x;
  const int lane = tid & 63, wid = tid >> 6;
  const int l15 = lane & 15, hi = lane >> 4;
  const int gid0 = blockIdx.x * 16;       // first global point of block
  const int b = gid0 >> 13;
  const int n0 = gid0 & 8191;

  // ---- stage bf16 weights into LDS (swizzled rows) ----
  {
    const uint4* wsrc = (const uint4*)&ws[WOFF_WMB];
    for (int t = tid; t < 1536; t += 256) {
      int m = t >> 9, r = t & 511;
      int c = r >> 3, q = r & 7;
      uint4 v = wsrc[t];
      *(uint4*)(wL + m*8192 + ((c*128 + q*16) ^ ((c&7)<<4))) = v;
    }
  }
  // ---- compute h for own column (col = tid) ----
  {
    const int pt = tid >> 4, kq = tid & 15;
    const size_t gq = (size_t)gid0 + pt;
    const int jh = ((const int*)&ws[OFF_IDX])[gq*16 + kq];
    const size_t gjh = (size_t)b*8192 + jh;
    const float4* Ar = (const float4*)&ws[OFF_R1 + gq*64];
    const float4* Br = (const float4*)&ws[OFF_R1 + gjh*64];
    const float4* Ur = (const float4*)&ws[WOFF_UD1];
    const int swzh = (tid & 7) << 4;
    #pragma unroll
    for (int t = 0; t < 16; ++t) {
      float4 a = Ar[t], bb = Br[t], u = Ur[t];
      float v0 = fmaxf(a.x - bb.x + u.x, 0.f);
      float v1 = fmaxf(a.y - bb.y + u.y, 0.f);
      float v2 = fmaxf(a.z - bb.z + u.z, 0.f);
      float v3 = fmaxf(a.w - bb.w + u.w, 0.f);
      *(uint2*)(hL + ((tid*128 + t*8) ^ swzh)) = make_uint2(bf2(v0,v1), bf2(v2,v3));
    }
  }
  __syncthreads();

  float* attnp = out + (size_t)2*64*8192;   // attn region after out0
  const f32x4 zf = {0.f, 0.f, 0.f, 0.f};

  for (int i = 0; i < 4; ++i) {
    const int ct = (wid << 2) + i;          // coltile == point index in block
    const int n = n0 + ct;
    const size_t gqc = (size_t)gid0 + ct;
    const int mycol = (ct << 4) + l15;
    const int swz = (mycol & 7) << 4;
    const int hbase = mycol*128 + hi*16;
    bf16x8 hb0 = *(const bf16x8*)(hL + ((hbase     ) ^ swz));
    bf16x8 hb1 = *(const bf16x8*)(hL + ((hbase + 64) ^ swz));
    const int jj = ((const int*)&ws[OFF_IDX])[gqc*16 + l15];
    const size_t gjc = (size_t)b*8192 + jj;

    // ---- D-GEMM (pos) + M-GEMM ----
    f32x4 accD[4], accM[4];
    #pragma unroll
    for (int rt = 0; rt < 4; ++rt) { accD[rt] = zf; accM[rt] = zf; }
    #pragma unroll
    for (int rt = 0; rt < 4; ++rt) {
      const int c = (rt << 4) + l15;
      const int ws2 = (c & 7) << 4;
      const int wb = c*128 + hi*16;
      bf16x8 m0 = *(const bf16x8*)(wL + (((wb     ) ^ ws2)));
      bf16x8 m1 = *(const bf16x8*)(wL + (((wb + 64) ^ ws2)));
      bf16x8 d0 = *(const bf16x8*)(wL + (8192 + ((wb     ) ^ ws2)));
      bf16x8 d1 = *(const bf16x8*)(wL + (8192 + ((wb + 64) ^ ws2)));
      accM[rt] = __builtin_amdgcn_mfma_f32_16x16x32_bf16(m0, hb0, accM[rt], 0, 0, 0);
      accM[rt] = __builtin_amdgcn_mfma_f32_16x16x32_bf16(m1, hb1, accM[rt], 0, 0, 0);
      accD[rt] = __builtin_amdgcn_mfma_f32_16x16x32_bf16(d0, hb0, accD[rt], 0, 0, 0);
      accD[rt] = __builtin_amdgcn_mfma_f32_16x16x32_bf16(d1, hb1, accD[rt], 0, 0, 0);
    }

    // ---- hg = relu(aM + P1[n] - G1[j] + vc), write bf16 back into hL (in place) ----
    #pragma unroll
    for (int rt = 0; rt < 4; ++rt) {
      const int c0 = (rt << 4) + (hi << 2);
      const float4 p1 = *(const float4*)&ws[OFF_P1 + gqc*64 + c0];
      const float4 g1 = *(const float4*)&ws[OFF_G1 + gjc*64 + c0];
      const float4 vc = *(const float4*)&ws[WOFF_VC + c0];
      float h0 = fmaxf(accM[rt][0] + p1.x - g1.x + vc.x, 0.f);
      float h1 = fmaxf(accM[rt][1] + p1.y - g1.y + vc.y, 0.f);
      float h2 = fmaxf(accM[rt][2] + p1.z - g1.z + vc.z, 0.f);
      float h3 = fmaxf(accM[rt][3] + p1.w - g1.w + vc.w, 0.f);
      *(uint2*)(hL + ((mycol*128 + (c0 << 1)) ^ swz)) = make_uint2(bf2(h0,h1), bf2(h2,h3));
    }

    // ---- G2-GEMM on hg (wave-local; DS ops are in-order within a wave) ----
    bf16x8 gb0 = *(const bf16x8*)(hL + ((hbase     ) ^ swz));
    bf16x8 gb1 = *(const bf16x8*)(hL + ((hbase + 64) ^ swz));
    f32x4 accG[4];
    #pragma unroll
    for (int rt = 0; rt < 4; ++rt) accG[rt] = zf;
    #pragma unroll
    for (int rt = 0; rt < 4; ++rt) {
      const int c = (rt << 4) + l15;
      const int ws2 = (c & 7) << 4;
      const int wb = c*128 + hi*16;
      bf16x8 g0 = *(const bf16x8*)(wL + (16384 + ((wb     ) ^ ws2)));
      bf16x8 g1f = *(const bf16x8*)(wL + (16384 + ((wb + 64) ^ ws2)));
      accG[rt] = __builtin_amdgcn_mfma_f32_16x16x32_bf16(g0,  gb0, accG[rt], 0, 0, 0);
      accG[rt] = __builtin_amdgcn_mfma_f32_16x16x32_bf16(g1f, gb1, accG[rt], 0, 0, 0);
    }

    // ---- softmax over kk (lane&15), attn store, y reduce ----
    #pragma unroll
    for (int rt = 0; rt < 4; ++rt) {
      const int c0 = (rt << 4) + (hi << 2);
      const float4 al = *(const float4*)&ws[OFF_AL + gjc*64 + c0];
      const float4 u2 = *(const float4*)&ws[WOFF_UD2 + c0];
      float y4[4];
      #pragma unroll
      for (int r = 0; r < 4; ++r) {
        float g = accG[rt][r];
        float mx = g;
        mx = fmaxf(mx, __shfl_xor(mx, 1));
        mx = fmaxf(mx, __shfl_xor(mx, 2));
        mx = fmaxf(mx, __shfl_xor(mx, 4));
        mx = fmaxf(mx, __shfl_xor(mx, 8));
        float e = __expf(g - mx);
        float sm = e;
        sm += __shfl_xor(sm, 1);
        sm += __shfl_xor(sm, 2);
        sm += __shfl_xor(sm, 4);
        sm += __shfl_xor(sm, 8);
        float rs;
        asm("v_rcp_f32 %0, %1" : "=v"(rs) : "v"(sm));
        float a = e * rs;
        attnp[(((size_t)(b*64 + c0 + r) << 13) + n)*16 + l15] = a;
        float pv = ((const float*)&al)[r] + accD[rt][r] + ((const float*)&u2)[r];
        float yv = a * pv;
        yv += __shfl_xor(yv, 1);
        yv += __shfl_xor(yv, 2);
        yv += __shfl_xor(yv, 4);
        yv += __shfl_xor(yv, 8);
        y4[r] = yv;
      }
      if (l15 == 0)
        *(float4*)&ws[OFF_Y + gqc*64 + c0] = make_float4(y4[0], y4[1], y4[2], y4[3]);
    }
  }
}

// =============== K4: out = Wdn*y + udn + input_x ===============
__global__ __launch_bounds__(256) void k4_out(const float* __restrict__ inx,
                                              float* __restrict__ ws,
                                              float* __restrict__ out)
{
  __shared__ float yS[16][64];
  __shared__ float wT[64][64];
  const int tid = threadIdx.x;
  const int pt = tid & 15, q = tid >> 4;   // channels q*4..q*4+3
  const int gid0 = blockIdx.x*16;
  const int b = gid0 >> 13, n0 = gid0 & 8191;
  for (int r = tid; r < 1024; r += 256) {
    int p2 = r >> 6, c = r & 63;
    yS[p2][c ^ p2] = ws[OFF_Y + (size_t)(gid0 + p2)*64 + c];
  }
  for (int r = tid; r < 4096; r += 256) {
    int o = r >> 6, i = r & 63;
    wT[i][WSWZ(i,o)] = ws[WOFF_WDN + r];
  }
  __syncthreads();
  float acc[4];
  #pragma unroll
  for (int i = 0; i < 4; ++i) acc[i] = ws[WOFF_UDN + q*4 + i];
  for (int ci = 0; ci < 64; ++ci) {
    float yv = yS[pt][ci ^ pt];
    const float4 w4 = *(const float4*)&wT[ci][WSWZ(ci, q*4)];
    acc[0] = fmaf(w4.x, yv, acc[0]);
    acc[1] = fmaf(w4.y, yv, acc[1]);
    acc[2] = fmaf(w4.z, yv, acc[2]);
    acc[3] = fmaf(w4.w, yv, acc[3]);
  }
  #pragma unroll
  for (int i = 0; i < 4; ++i) {
    const int c = q*4 + i;
    size_t o = ((size_t)(b*64 + c) << 13) + n0 + pt;
    out[o] = acc[i] + inx[o];
  }
}

extern "C" void kernel_launch(void* const* d_in, const int* in_sizes, int n_in,
                              void* d_out, int out_size, void* d_ws, size_t ws_size,
                              hipStream_t stream)
{
  (void)in_sizes; (void)n_in; (void)out_size; (void)ws_size;
  float* ws = (float*)d_ws;
  const float* inp = (const float*)d_in[0];
  const float* inx = (const float*)d_in[1];
  float* out = (float*)d_out;
  P32 P;
  for (int i = 0; i < 32; ++i) P.a[i] = (const float*)d_in[i];

  k0_fold   <<<8,      256, 0, stream>>>(P, ws);
  k0b_pack  <<<3,      256, 0, stream>>>(ws);
  k1_feat   <<<BN/16,  256, 0, stream>>>(inp, inx, ws);
  k2_topk   <<<BN/4,   256, 0, stream>>>(ws);
  k3_mfma   <<<BN/16,  256, 0, stream>>>(ws, out);
  k4_out    <<<BN/16,  256, 0, stream>>>(inx, ws, out);
}

// Round 15
// 281.043 us; speedup vs baseline: 4.2628x; 1.0434x over previous
//
#include <hip/hip_runtime.h>
#include <cfloat>

#define BN 16384   // B*N = 2*8192

// ---------------- workspace layout (float words) ----------------
#define WOFF_WT    0
#define WOFF_P1M   4096
#define WOFF_G1M   8192
#define WOFF_MMT   12288
#define WOFF_WD2T  16384
#define WOFF_G2T   20480
#define WOFF_WDN   24576
#define WOFF_WAL   28672
#define WOFF_WD1   32768
#define WOFF_BT    33024
#define WOFF_BAL   33088
#define WOFF_VC    33152
#define WOFF_UD1   33216
#define WOFF_UD2   33280
#define WOFF_UDN   33344
// bf16-packed (u32 pair) row-major weight copies for MFMA (filled by k0b)
#define WOFF_WMB   33792   // Wm  [c][cp] 2048 u32
#define WOFF_WD2B  35840   // Wd2s[c][cp] 2048 u32
#define WOFF_G2B   37888   // G2s [c][cp] 2048 u32
#define WB         39936

static constexpr size_t OFF_P1   = WB;                           // [BN][64]
static constexpr size_t OFF_G1   = OFF_P1 + (size_t)BN*64;       // [BN][64]
static constexpr size_t OFF_AL   = OFF_G1 + (size_t)BN*64;       // [BN][64]
static constexpr size_t OFF_R1   = OFF_AL + (size_t)BN*64;       // [BN][64]
static constexpr size_t OFF_P4   = OFF_R1 + (size_t)BN*64;       // [BN] float4 (x,y,z,sq)
static constexpr size_t OFF_IDX  = OFF_P4 + (size_t)BN*4;        // [BN][16] int
static constexpr size_t OFF_Y    = OFF_IDX + (size_t)BN*16;      // [BN][64]

struct P32 { const float* a[32]; };

#define WSWZ(i,o) ((o) ^ (((i)&7)<<2))

typedef __attribute__((ext_vector_type(8))) short bf16x8;
typedef __attribute__((ext_vector_type(4))) float f32x4;

__device__ __forceinline__ unsigned bf2(float lo, float hi) {
  unsigned a = __float_as_uint(lo); a = (a + 0x7fffu + ((a>>16)&1u)) >> 16;
  unsigned b = __float_as_uint(hi); b = (b + 0x7fffu + ((b>>16)&1u)) & 0xffff0000u;
  return a | b;
}

// =============== K0: fold weights ===============
__global__ __launch_bounds__(256) void k0_fold(P32 P, float* __restrict__ ws)
{
  const int bid = blockIdx.x, tid = threadIdx.x;
  const float* Wtop = P.a[2];  const float* btop = P.a[3];
  const float* stop = P.a[4];  const float* ttop = P.a[5];
  const float* Wphi = P.a[6];  const float* bphi = P.a[7];
  const float* Wpsi = P.a[8];  const float* bpsi = P.a[9];
  const float* Wal  = P.a[10]; const float* bal  = P.a[11];
  const float* Wg1  = P.a[12]; const float* bg1  = P.a[13];
  const float* sg1  = P.a[14]; const float* tg1  = P.a[15];
  const float* Wg2  = P.a[16];
  const float* sg2  = P.a[18];
  const float* Wd1  = P.a[20]; const float* bd1  = P.a[21];
  const float* sd1  = P.a[22]; const float* td1  = P.a[23];
  const float* Wd2  = P.a[24]; const float* bd2  = P.a[25];
  const float* sd2  = P.a[26]; const float* td2  = P.a[27];
  const float* Wdn  = P.a[28]; const float* bdn  = P.a[29];
  const float* sdn  = P.a[30]; const float* tdn  = P.a[31];

  if (bid == 0) {
    for (int e = tid; e < 4096; e += 256) { int o = e >> 6; ws[WOFF_WT + e] = stop[o]*Wtop[e]; }
    if (tid < 64) {
      ws[WOFF_BT  + tid] = stop[tid]*btop[tid] + ttop[tid];
      ws[WOFF_BAL + tid] = bal[tid];
      ws[WOFF_UD1 + tid] = sd1[tid]*bd1[tid] + td1[tid];
      ws[WOFF_UD2 + tid] = sd2[tid]*bd2[tid] + td2[tid];
      ws[WOFF_UDN + tid] = sdn[tid]*bdn[tid] + tdn[tid];
      float acc = 0.f;
      for (int c = 0; c < 64; ++c)
        acc += Wg1[tid*64+c] * (bphi[c] - bpsi[c] + sd2[c]*bd2[c] + td2[c]);
      ws[WOFF_VC + tid] = sg1[tid]*(acc + bg1[tid]) + tg1[tid];
    }
  } else if (bid == 1) {          // P1m[o][i] = s_g1[o] * (Wg1 Wphi)[o][i]
    for (int e = tid; e < 4096; e += 256) {
      int o = e >> 6, i = e & 63; float a = 0.f;
      for (int c = 0; c < 64; ++c) a += Wg1[o*64+c]*Wphi[c*64+i];
      ws[WOFF_P1M + e] = sg1[o]*a;
    }
  } else if (bid == 2) {          // G1m
    for (int e = tid; e < 4096; e += 256) {
      int o = e >> 6, i = e & 63; float a = 0.f;
      for (int c = 0; c < 64; ++c) a += Wg1[o*64+c]*Wpsi[c*64+i];
      ws[WOFF_G1M + e] = sg1[o]*a;
    }
  } else if (bid == 3) {          // MmT[cp][c] = s_g1[c] * (Wg1 diag(sd2) Wd2)[c][cp]
    for (int e = tid; e < 4096; e += 256) {
      int cp = e >> 6, c = e & 63; float a = 0.f;
      for (int u = 0; u < 64; ++u) a += Wg1[c*64+u]*sd2[u]*Wd2[u*64+cp];
      ws[WOFF_MMT + e] = sg1[c]*a;
    }
  } else if (bid == 4) {          // Wd2T[cp][c] ; Wd1f
    for (int e = tid; e < 4096; e += 256) {
      int cp = e >> 6, c = e & 63;
      ws[WOFF_WD2T + e] = sd2[c]*Wd2[c*64+cp];
    }
    if (tid < 192) ws[WOFF_WD1 + tid] = sd1[tid/3]*Wd1[tid];
  } else if (bid == 5) {          // G2T[cp][c]
    for (int e = tid; e < 4096; e += 256) {
      int cp = e >> 6, c = e & 63;
      ws[WOFF_G2T + e] = sg2[c]*Wg2[c*64+cp];
    }
  } else if (bid == 6) {          // Wdn row-major
    for (int e = tid; e < 4096; e += 256) { int o = e >> 6; ws[WOFF_WDN + e] = sdn[o]*Wdn[e]; }
  } else {                        // W_alpha copy
    for (int e = tid; e < 4096; e += 256) ws[WOFF_WAL + e] = Wal[e];
  }
}

// =============== K0b: pack MFMA weights to bf16 row-major [c][cp] ===============
__global__ __launch_bounds__(256) void k0b_pack(float* __restrict__ ws)
{
  const int m = blockIdx.x;                    // 0:Wm 1:Wd2s 2:G2s
  const int srcO = (m==0) ? WOFF_MMT : (m==1) ? WOFF_WD2T : WOFF_G2T;   // [cp][c] fp32
  const int dstO = (m==0) ? WOFF_WMB : (m==1) ? WOFF_WD2B : WOFF_G2B;   // [c][cp] bf16 pairs
  unsigned* dst = (unsigned*)&ws[dstO];
  for (int w = threadIdx.x; w < 2048; w += 256) {
    int c = w >> 5, pair = w & 31;
    float v0 = ws[srcO + (pair*2  )*64 + c];
    float v1 = ws[srcO + (pair*2+1)*64 + c];
    dst[w] = bf2(v0, v1);
  }
}

// =============== K1: per-point features (x -> P1,G1,AL) + r1 + p4 ===============
__global__ __launch_bounds__(256) void k1_feat(const float* __restrict__ inp,
                                               const float* __restrict__ inx,
                                               float* __restrict__ ws)
{
  __shared__ float tX[64][16];   // [c][pt]
  __shared__ float wT[64][64];   // transposed + swizzled weights
  const int tid = threadIdx.x;
  const int pt = tid & 15, q = tid >> 4;   // q in [0,16): channels q*4..q*4+3
  const int gid0 = blockIdx.x * 16;
  const int b = gid0 >> 13, n0 = gid0 & 8191;
  const size_t gq = (size_t)gid0 + pt;

  for (int r = tid; r < 1024; r += 256) {
    int c = r >> 4, col = r & 15;
    tX[c][col] = inx[((size_t)(b*64 + c) << 13) + n0 + col];
  }
  for (int r = tid; r < 4096; r += 256) {
    int o = r >> 6, i = r & 63;
    wT[i][WSWZ(i,o)] = ws[WOFF_WT + r];
  }
  __syncthreads();

  float acc[4];
  #pragma unroll
  for (int i = 0; i < 4; ++i) acc[i] = ws[WOFF_BT + q*4 + i];
  for (int ci = 0; ci < 64; ++ci) {
    float xv = tX[ci][pt];
    const float4 w4 = *(const float4*)&wT[ci][WSWZ(ci, q*4)];
    acc[0] = fmaf(w4.x, xv, acc[0]);
    acc[1] = fmaf(w4.y, xv, acc[1]);
    acc[2] = fmaf(w4.z, xv, acc[2]);
    acc[3] = fmaf(w4.w, xv, acc[3]);
  }
  __syncthreads();
  #pragma unroll
  for (int i = 0; i < 4; ++i) tX[q*4 + i][pt] = acc[i];

  // p4 + r1 (global only)
  {
    size_t pb = (size_t)b*3*8192 + n0 + pt;
    float px = inp[pb], py = inp[pb + 8192], pz = inp[pb + 16384];
    float sq = __fadd_rn(__fadd_rn(__fmul_rn(px,px), __fmul_rn(py,py)), __fmul_rn(pz,pz));
    if (q == 0) *(float4*)&ws[OFF_P4 + gq*4] = make_float4(px,py,pz,sq);
    float r1v[4];
    #pragma unroll
    for (int i = 0; i < 4; ++i) {
      int c = q*4 + i;
      float a = ws[WOFF_WD1 + c*3+0]*px;
      a = fmaf(ws[WOFF_WD1 + c*3+1], py, a);
      a = fmaf(ws[WOFF_WD1 + c*3+2], pz, a);
      r1v[i] = a;
    }
    *(float4*)&ws[OFF_R1 + gq*64 + q*4] = make_float4(r1v[0], r1v[1], r1v[2], r1v[3]);
  }
  __syncthreads();

  #pragma unroll
  for (int m = 0; m < 3; ++m) {
    const int    mof = (m==0) ? WOFF_P1M : (m==1) ? WOFF_G1M : WOFF_WAL;
    const size_t oof = (m==0) ? OFF_P1   : (m==1) ? OFF_G1   : OFF_AL;
    __syncthreads();
    for (int r = tid; r < 4096; r += 256) {
      int o = r >> 6, i = r & 63;
      wT[i][WSWZ(i,o)] = ws[mof + r];
    }
    __syncthreads();
    #pragma unroll
    for (int i = 0; i < 4; ++i) acc[i] = (m == 2) ? ws[WOFF_BAL + q*4 + i] : 0.f;
    for (int ci = 0; ci < 64; ++ci) {
      float xv = tX[ci][pt];
      const float4 w4 = *(const float4*)&wT[ci][WSWZ(ci, q*4)];
      acc[0] = fmaf(w4.x, xv, acc[0]);
      acc[1] = fmaf(w4.y, xv, acc[1]);
      acc[2] = fmaf(w4.z, xv, acc[2]);
      acc[3] = fmaf(w4.w, xv, acc[3]);
    }
    *(float4*)&ws[oof + gq*64 + q*4] = make_float4(acc[0], acc[1], acc[2], acc[3]);
  }
}

// numpy-exact distance
__device__ __forceinline__ float pdist(const float4 q4, const float4 c4) {
  float m = __fadd_rn(__fadd_rn(__fmul_rn(q4.x,c4.x), __fmul_rn(q4.y,c4.y)), __fmul_rn(q4.z,c4.z));
  return __fsub_rn(__fadd_rn(q4.w, c4.w), __fmul_rn(2.f, m));
}

__device__ __forceinline__ unsigned dmono(float d) {
  unsigned db = __float_as_uint(d);
  return db ^ (((int)db < 0) ? 0xffffffffu : 0x80000000u);
}

// branchless sorted insert into 5-slot ascending list, 32-bit d-keys + parallel idx.
// '<=' keeps the incumbent on d-ties; within a lane stream idx is strictly increasing,
// so tie order == ascending idx == reference lex-(d,idx) order.
__device__ __forceinline__ void ins5_32(unsigned& d0, unsigned& d1, unsigned& d2,
                                        unsigned& d3, unsigned& d4,
                                        unsigned& i0, unsigned& i1, unsigned& i2,
                                        unsigned& i3, unsigned& i4,
                                        unsigned xd, unsigned xi)
{
  unsigned td, ti;
  bool c;
  c = (d0 <= xd);  td = c ? d0 : xd;  ti = c ? i0 : xi;  xd = c ? xd : d0;  xi = c ? xi : i0;  d0 = td; i0 = ti;
  c = (d1 <= xd);  td = c ? d1 : xd;  ti = c ? i1 : xi;  xd = c ? xd : d1;  xi = c ? xi : i1;  d1 = td; i1 = ti;
  c = (d2 <= xd);  td = c ? d2 : xd;  ti = c ? i2 : xi;  xd = c ? xd : d2;  xi = c ? xi : i2;  d2 = td; i2 = ti;
  c = (d3 <= xd);  td = c ? d3 : xd;  ti = c ? i3 : xi;  xd = c ? xd : d3;  xi = c ? xi : i3;  d3 = td; i3 = ti;
  c = (d4 <= xd);  d4 = c ? d4 : xd;  i4 = c ? i4 : xi;
}

// =============== K2: exact top-16 KNN, single pass (wave-per-query) ===============
// R14 structure; ladder now 32-bit d + parallel idx (u64 keys rebuilt only for the
// 5 survivors). Soundness identical: every dropped element is strictly greater
// (u64-lex) than the lane's final 5th slot; if all lanes' savedk4 >= m16 the union
// provably contains the true top-16, else guaranteed serial rescan.
__global__ __launch_bounds__(256) void k2_topk(float* __restrict__ ws)
{
  __shared__ float4 tile[1024];   // 16 KB
  const int tid = threadIdx.x;
  const int lane = tid & 63, w = tid >> 6;
  const int gid = blockIdx.x*4 + w;
  const int b = gid >> 13;
  const float4 q4 = *(const float4*)&ws[OFF_P4 + (size_t)gid*4];
  const float4* cp4 = (const float4*)&ws[OFF_P4 + (size_t)b*8192*4];
  int* ib = (int*)&ws[OFF_IDX];

  unsigned d0=~0u,d1=~0u,d2=~0u,d3=~0u,d4=~0u;
  unsigned i0=~0u,i1=~0u,i2=~0u,i3=~0u,i4=~0u;

  #pragma unroll 1
  for (int c0 = 0; c0 < 8192; c0 += 1024) {
    __syncthreads();
    #pragma unroll
    for (int t = 0; t < 4; ++t) tile[tid + t*256] = cp4[c0 + tid + t*256];
    __syncthreads();
    #pragma unroll 8
    for (int r = 0; r < 16; ++r) {
      const int ci = r*64 + lane;
      float d = pdist(q4, tile[ci]);
      ins5_32(d0,d1,d2,d3,d4, i0,i1,i2,i3,i4, dmono(d), (unsigned)(c0 + ci));
    }
  }

  // rebuild u64 keys for the 5 survivors
  unsigned long long k0 = ((unsigned long long)d0 << 32) | i0;
  unsigned long long k1 = ((unsigned long long)d1 << 32) | i1;
  unsigned long long k2 = ((unsigned long long)d2 << 32) | i2;
  unsigned long long k3 = ((unsigned long long)d3 << 32) | i3;
  unsigned long long k4 = ((unsigned long long)d4 << 32) | i4;
  const unsigned long long savedk4 = k4;

  // 16 wave-argmin rounds over the 320-key union (5 keys/lane)
  unsigned myres = 0u;
  unsigned long long m = 0ull;
  #pragma unroll 1
  for (int r = 0; r < 16; ++r) {
    unsigned long long a01 = (k0 < k1) ? k0 : k1;
    unsigned long long a23 = (k2 < k3) ? k2 : k3;
    unsigned long long a03 = (a01 < a23) ? a01 : a23;
    m = (a03 < k4) ? a03 : k4;
    #pragma unroll
    for (int s = 1; s < 64; s <<= 1) {
      unsigned long long o = __shfl_xor(m, s);
      m = (o < m) ? o : m;
    }
    k0 = (k0 == m) ? ~0ull : k0;  k1 = (k1 == m) ? ~0ull : k1;
    k2 = (k2 == m) ? ~0ull : k2;  k3 = (k3 == m) ? ~0ull : k3;
    k4 = (k4 == m) ? ~0ull : k4;
    if (lane == r) myres = (unsigned)(m & 0xffffffffu);
  }

  // safety check: m (last round) is the 16th-smallest of the union
  const bool unsafe = __ballot(savedk4 < m) != 0ull;
  if (!unsafe) {
    if (lane < 16) ib[(size_t)gid*16 + lane] = (int)myres;
  } else {
    // guaranteed-correct fallback (~2.6e-4 per query): serial rescan
    if (lane == 0) {
      float ds[16]; int is[16];
      #pragma unroll
      for (int r = 0; r < 16; ++r) { ds[r] = FLT_MAX; is[r] = 0x7fffffff; }
      for (int t = 0; t < 8192; ++t) {
        float d = pdist(q4, cp4[t]);
        if (d < ds[15]) {
          #pragma unroll
          for (int s = 15; s >= 0; --s) {
            bool bs = d < ds[s];
            bool bm = (s > 0) ? (d < ds[s-1]) : false;
            float dn = bs ? (bm ? ds[s-1] : d) : ds[s];
            int   jn = bs ? (bm ? is[s-1] : t) : is[s];
            ds[s] = dn; is[s] = jn;
          }
        }
      }
      #pragma unroll
      for (int r = 0; r < 16; ++r) ib[(size_t)gid*16 + r] = is[r];
    }
  }
}

// =============== K3 (MFMA): fused per-point block (weights in LDS, 16 pts/block) ===============
__global__ __launch_bounds__(256) void k3_mfma(float* __restrict__ ws, float* __restrict__ out)
{
  __shared__ __align__(16) unsigned char wL[24576];  // 3 x [64 c][64 cp] bf16, swizzled
  __shared__ __align__(16) unsigned char hL[32768];  // [256 col][64 cp] bf16, swizzled
  const int tid = threadIdx.x;
  const int lane = tid & 63, wid = tid >> 6;
  const int l15 = lane & 15, hi = lane >> 4;
  const int gid0 = blockIdx.x * 16;       // first global point of block
  const int b = gid0 >> 13;
  const int n0 = gid0 & 8191;

  // ---- stage bf16 weights into LDS (swizzled rows) ----
  {
    const uint4* wsrc = (const uint4*)&ws[WOFF_WMB];
    for (int t = tid; t < 1536; t += 256) {
      int m = t >> 9, r = t & 511;
      int c = r >> 3, q = r & 7;
      uint4 v = wsrc[t];
      *(uint4*)(wL + m*8192 + ((c*128 + q*16) ^ ((c&7)<<4))) = v;
    }
  }
  // ---- compute h for own column (col = tid) ----
  {
    const int pt = tid >> 4, kq = tid & 15;
    const size_t gq = (size_t)gid0 + pt;
    const int jh = ((const int*)&ws[OFF_IDX])[gq*16 + kq];
    const size_t gjh = (size_t)b*8192 + jh;
    const float4* Ar = (const float4*)&ws[OFF_R1 + gq*64];
    const float4* Br = (const float4*)&ws[OFF_R1 + gjh*64];
    const float4* Ur = (const float4*)&ws[WOFF_UD1];
    const int swzh = (tid & 7) << 4;
    #pragma unroll
    for (int t = 0; t < 16; ++t) {
      float4 a = Ar[t], bb = Br[t], u = Ur[t];
      float v0 = fmaxf(a.x - bb.x + u.x, 0.f);
      float v1 = fmaxf(a.y - bb.y + u.y, 0.f);
      float v2 = fmaxf(a.z - bb.z + u.z, 0.f);
      float v3 = fmaxf(a.w - bb.w + u.w, 0.f);
      *(uint2*)(hL + ((tid*128 + t*8) ^ swzh)) = make_uint2(bf2(v0,v1), bf2(v2,v3));
    }
  }
  __syncthreads();

  float* attnp = out + (size_t)2*64*8192;   // attn region after out0
  const f32x4 zf = {0.f, 0.f, 0.f, 0.f};

  for (int i = 0; i < 4; ++i) {
    const int ct = (wid << 2) + i;          // coltile == point index in block
    const int n = n0 + ct;
    const size_t gqc = (size_t)gid0 + ct;
    const int mycol = (ct << 4) + l15;
    const int swz = (mycol & 7) << 4;
    const int hbase = mycol*128 + hi*16;
    bf16x8 hb0 = *(const bf16x8*)(hL + ((hbase     ) ^ swz));
    bf16x8 hb1 = *(const bf16x8*)(hL + ((hbase + 64) ^ swz));
    const int jj = ((const int*)&ws[OFF_IDX])[gqc*16 + l15];
    const size_t gjc = (size_t)b*8192 + jj;

    // ---- D-GEMM (pos) + M-GEMM ----
    f32x4 accD[4], accM[4];
    #pragma unroll
    for (int rt = 0; rt < 4; ++rt) { accD[rt] = zf; accM[rt] = zf; }
    #pragma unroll
    for (int rt = 0; rt < 4; ++rt) {
      const int c = (rt << 4) + l15;
      const int ws2 = (c & 7) << 4;
      const int wb = c*128 + hi*16;
      bf16x8 m0 = *(const bf16x8*)(wL + (((wb     ) ^ ws2)));
      bf16x8 m1 = *(const bf16x8*)(wL + (((wb + 64) ^ ws2)));
      bf16x8 d0 = *(const bf16x8*)(wL + (8192 + ((wb     ) ^ ws2)));
      bf16x8 d1 = *(const bf16x8*)(wL + (8192 + ((wb + 64) ^ ws2)));
      accM[rt] = __builtin_amdgcn_mfma_f32_16x16x32_bf16(m0, hb0, accM[rt], 0, 0, 0);
      accM[rt] = __builtin_amdgcn_mfma_f32_16x16x32_bf16(m1, hb1, accM[rt], 0, 0, 0);
      accD[rt] = __builtin_amdgcn_mfma_f32_16x16x32_bf16(d0, hb0, accD[rt], 0, 0, 0);
      accD[rt] = __builtin_amdgcn_mfma_f32_16x16x32_bf16(d1, hb1, accD[rt], 0, 0, 0);
    }

    // ---- hg = relu(aM + P1[n] - G1[j] + vc), write bf16 back into hL (in place) ----
    #pragma unroll
    for (int rt = 0; rt < 4; ++rt) {
      const int c0 = (rt << 4) + (hi << 2);
      const float4 p1 = *(const float4*)&ws[OFF_P1 + gqc*64 + c0];
      const float4 g1 = *(const float4*)&ws[OFF_G1 + gjc*64 + c0];
      const float4 vc = *(const float4*)&ws[WOFF_VC + c0];
      float h0 = fmaxf(accM[rt][0] + p1.x - g1.x + vc.x, 0.f);
      float h1 = fmaxf(accM[rt][1] + p1.y - g1.y + vc.y, 0.f);
      float h2 = fmaxf(accM[rt][2] + p1.z - g1.z + vc.z, 0.f);
      float h3 = fmaxf(accM[rt][3] + p1.w - g1.w + vc.w, 0.f);
      *(uint2*)(hL + ((mycol*128 + (c0 << 1)) ^ swz)) = make_uint2(bf2(h0,h1), bf2(h2,h3));
    }

    // ---- G2-GEMM on hg (wave-local; DS ops are in-order within a wave) ----
    bf16x8 gb0 = *(const bf16x8*)(hL + ((hbase     ) ^ swz));
    bf16x8 gb1 = *(const bf16x8*)(hL + ((hbase + 64) ^ swz));
    f32x4 accG[4];
    #pragma unroll
    for (int rt = 0; rt < 4; ++rt) accG[rt] = zf;
    #pragma unroll
    for (int rt = 0; rt < 4; ++rt) {
      const int c = (rt << 4) + l15;
      const int ws2 = (c & 7) << 4;
      const int wb = c*128 + hi*16;
      bf16x8 g0 = *(const bf16x8*)(wL + (16384 + ((wb     ) ^ ws2)));
      bf16x8 g1f = *(const bf16x8*)(wL + (16384 + ((wb + 64) ^ ws2)));
      accG[rt] = __builtin_amdgcn_mfma_f32_16x16x32_bf16(g0,  gb0, accG[rt], 0, 0, 0);
      accG[rt] = __builtin_amdgcn_mfma_f32_16x16x32_bf16(g1f, gb1, accG[rt], 0, 0, 0);
    }

    // ---- softmax over kk (lane&15), attn store, y reduce ----
    #pragma unroll
    for (int rt = 0; rt < 4; ++rt) {
      const int c0 = (rt << 4) + (hi << 2);
      const float4 al = *(const float4*)&ws[OFF_AL + gjc*64 + c0];
      const float4 u2 = *(const float4*)&ws[WOFF_UD2 + c0];
      float y4[4];
      #pragma unroll
      for (int r = 0; r < 4; ++r) {
        float g = accG[rt][r];
        float mx = g;
        mx = fmaxf(mx, __shfl_xor(mx, 1));
        mx = fmaxf(mx, __shfl_xor(mx, 2));
        mx = fmaxf(mx, __shfl_xor(mx, 4));
        mx = fmaxf(mx, __shfl_xor(mx, 8));
        float e = __expf(g - mx);
        float sm = e;
        sm += __shfl_xor(sm, 1);
        sm += __shfl_xor(sm, 2);
        sm += __shfl_xor(sm, 4);
        sm += __shfl_xor(sm, 8);
        float rs;
        asm("v_rcp_f32 %0, %1" : "=v"(rs) : "v"(sm));
        float a = e * rs;
        attnp[(((size_t)(b*64 + c0 + r) << 13) + n)*16 + l15] = a;
        float pv = ((const float*)&al)[r] + accD[rt][r] + ((const float*)&u2)[r];
        float yv = a * pv;
        yv += __shfl_xor(yv, 1);
        yv += __shfl_xor(yv, 2);
        yv += __shfl_xor(yv, 4);
        yv += __shfl_xor(yv, 8);
        y4[r] = yv;
      }
      if (l15 == 0)
        *(float4*)&ws[OFF_Y + gqc*64 + c0] = make_float4(y4[0], y4[1], y4[2], y4[3]);
    }
  }
}

// =============== K4: out = Wdn*y + udn + input_x ===============
__global__ __launch_bounds__(256) void k4_out(const float* __restrict__ inx,
                                              float* __restrict__ ws,
                                              float* __restrict__ out)
{
  __shared__ float yS[16][64];
  __shared__ float wT[64][64];
  const int tid = threadIdx.x;
  const int pt = tid & 15, q = tid >> 4;   // channels q*4..q*4+3
  const int gid0 = blockIdx.x*16;
  const int b = gid0 >> 13, n0 = gid0 & 8191;
  for (int r = tid; r < 1024; r += 256) {
    int p2 = r >> 6, c = r & 63;
    yS[p2][c ^ p2] = ws[OFF_Y + (size_t)(gid0 + p2)*64 + c];
  }
  for (int r = tid; r < 4096; r += 256) {
    int o = r >> 6, i = r & 63;
    wT[i][WSWZ(i,o)] = ws[WOFF_WDN + r];
  }
  __syncthreads();
  float acc[4];
  #pragma unroll
  for (int i = 0; i < 4; ++i) acc[i] = ws[WOFF_UDN + q*4 + i];
  for (int ci = 0; ci < 64; ++ci) {
    float yv = yS[pt][ci ^ pt];
    const float4 w4 = *(const float4*)&wT[ci][WSWZ(ci, q*4)];
    acc[0] = fmaf(w4.x, yv, acc[0]);
    acc[1] = fmaf(w4.y, yv, acc[1]);
    acc[2] = fmaf(w4.z, yv, acc[2]);
    acc[3] = fmaf(w4.w, yv, acc[3]);
  }
  #pragma unroll
  for (int i = 0; i < 4; ++i) {
    const int c = q*4 + i;
    size_t o = ((size_t)(b*64 + c) << 13) + n0 + pt;
    out[o] = acc[i] + inx[o];
  }
}

extern "C" void kernel_launch(void* const* d_in, const int* in_sizes, int n_in,
                              void* d_out, int out_size, void* d_ws, size_t ws_size,
                              hipStream_t stream)
{
  (void)in_sizes; (void)n_in; (void)out_size; (void)ws_size;
  float* ws = (float*)d_ws;
  const float* inp = (const float*)d_in[0];
  const float* inx = (const float*)d_in[1];
  float* out = (float*)d_out;
  P32 P;
  for (int i = 0; i < 32; ++i) P.a[i] = (const float*)d_in[i];

  k0_fold   <<<8,      256, 0, stream>>>(P, ws);
  k0b_pack  <<<3,      256, 0, stream>>>(ws);
  k1_feat   <<<BN/16,  256, 0, stream>>>(inp, inx, ws);
  k2_topk   <<<BN/4,   256, 0, stream>>>(ws);
  k3_mfma   <<<BN/16,  256, 0, stream>>>(ws, out);
  k4_out    <<<BN/16,  256, 0, stream>>>(inx, ws, out);
}

// Round 16
// 268.391 us; speedup vs baseline: 4.4638x; 1.0471x over previous
//
#include <hip/hip_runtime.h>
#include <cfloat>

#define BN 16384   // B*N = 2*8192

// ---------------- workspace layout (float words) ----------------
#define WOFF_WT    0
#define WOFF_P1M   4096
#define WOFF_G1M   8192
#define WOFF_MMT   12288
#define WOFF_WD2T  16384
#define WOFF_G2T   20480
#define WOFF_WDN   24576
#define WOFF_WAL   28672
#define WOFF_WD1   32768
#define WOFF_BT    33024
#define WOFF_BAL   33088
#define WOFF_VC    33152
#define WOFF_UD1   33216
#define WOFF_UD2   33280
#define WOFF_UDN   33344
// bf16-packed (u32 pair) row-major weight copies for MFMA (filled by k0b)
#define WOFF_WMB   33792   // Wm  [c][cp] 2048 u32
#define WOFF_WD2B  35840   // Wd2s[c][cp] 2048 u32
#define WOFF_G2B   37888   // G2s [c][cp] 2048 u32
#define WB         39936

static constexpr size_t OFF_P1   = WB;                           // [BN][64]
static constexpr size_t OFF_G1   = OFF_P1 + (size_t)BN*64;       // [BN][64]
static constexpr size_t OFF_AL   = OFF_G1 + (size_t)BN*64;       // [BN][64]
static constexpr size_t OFF_R1   = OFF_AL + (size_t)BN*64;       // [BN][64]
static constexpr size_t OFF_P4   = OFF_R1 + (size_t)BN*64;       // [BN] float4 (x,y,z,sq)
static constexpr size_t OFF_IDX  = OFF_P4 + (size_t)BN*4;        // [BN][16] int
static constexpr size_t OFF_Y    = OFF_IDX + (size_t)BN*16;      // [BN][64]
static constexpr size_t OFF_P4M  = OFF_Y + (size_t)BN*64;        // [BN] float4 (-2x,-2y,-2z,sq)

struct P32 { const float* a[32]; };

#define WSWZ(i,o) ((o) ^ (((i)&7)<<2))

typedef __attribute__((ext_vector_type(8))) short bf16x8;
typedef __attribute__((ext_vector_type(4))) float f32x4;

__device__ __forceinline__ unsigned bf2(float lo, float hi) {
  unsigned a = __float_as_uint(lo); a = (a + 0x7fffu + ((a>>16)&1u)) >> 16;
  unsigned b = __float_as_uint(hi); b = (b + 0x7fffu + ((b>>16)&1u)) & 0xffff0000u;
  return a | b;
}

// =============== K0: fold weights ===============
__global__ __launch_bounds__(256) void k0_fold(P32 P, float* __restrict__ ws)
{
  const int bid = blockIdx.x, tid = threadIdx.x;
  const float* Wtop = P.a[2];  const float* btop = P.a[3];
  const float* stop = P.a[4];  const float* ttop = P.a[5];
  const float* Wphi = P.a[6];  const float* bphi = P.a[7];
  const float* Wpsi = P.a[8];  const float* bpsi = P.a[9];
  const float* Wal  = P.a[10]; const float* bal  = P.a[11];
  const float* Wg1  = P.a[12]; const float* bg1  = P.a[13];
  const float* sg1  = P.a[14]; const float* tg1  = P.a[15];
  const float* Wg2  = P.a[16];
  const float* sg2  = P.a[18];
  const float* Wd1  = P.a[20]; const float* bd1  = P.a[21];
  const float* sd1  = P.a[22]; const float* td1  = P.a[23];
  const float* Wd2  = P.a[24]; const float* bd2  = P.a[25];
  const float* sd2  = P.a[26]; const float* td2  = P.a[27];
  const float* Wdn  = P.a[28]; const float* bdn  = P.a[29];
  const float* sdn  = P.a[30]; const float* tdn  = P.a[31];

  if (bid == 0) {
    for (int e = tid; e < 4096; e += 256) { int o = e >> 6; ws[WOFF_WT + e] = stop[o]*Wtop[e]; }
    if (tid < 64) {
      ws[WOFF_BT  + tid] = stop[tid]*btop[tid] + ttop[tid];
      ws[WOFF_BAL + tid] = bal[tid];
      ws[WOFF_UD1 + tid] = sd1[tid]*bd1[tid] + td1[tid];
      ws[WOFF_UD2 + tid] = sd2[tid]*bd2[tid] + td2[tid];
      ws[WOFF_UDN + tid] = sdn[tid]*bdn[tid] + tdn[tid];
      float acc = 0.f;
      for (int c = 0; c < 64; ++c)
        acc += Wg1[tid*64+c] * (bphi[c] - bpsi[c] + sd2[c]*bd2[c] + td2[c]);
      ws[WOFF_VC + tid] = sg1[tid]*(acc + bg1[tid]) + tg1[tid];
    }
  } else if (bid == 1) {          // P1m[o][i] = s_g1[o] * (Wg1 Wphi)[o][i]
    for (int e = tid; e < 4096; e += 256) {
      int o = e >> 6, i = e & 63; float a = 0.f;
      for (int c = 0; c < 64; ++c) a += Wg1[o*64+c]*Wphi[c*64+i];
      ws[WOFF_P1M + e] = sg1[o]*a;
    }
  } else if (bid == 2) {          // G1m
    for (int e = tid; e < 4096; e += 256) {
      int o = e >> 6, i = e & 63; float a = 0.f;
      for (int c = 0; c < 64; ++c) a += Wg1[o*64+c]*Wpsi[c*64+i];
      ws[WOFF_G1M + e] = sg1[o]*a;
    }
  } else if (bid == 3) {          // MmT[cp][c] = s_g1[c] * (Wg1 diag(sd2) Wd2)[c][cp]
    for (int e = tid; e < 4096; e += 256) {
      int cp = e >> 6, c = e & 63; float a = 0.f;
      for (int u = 0; u < 64; ++u) a += Wg1[c*64+u]*sd2[u]*Wd2[u*64+cp];
      ws[WOFF_MMT + e] = sg1[c]*a;
    }
  } else if (bid == 4) {          // Wd2T[cp][c] ; Wd1f
    for (int e = tid; e < 4096; e += 256) {
      int cp = e >> 6, c = e & 63;
      ws[WOFF_WD2T + e] = sd2[c]*Wd2[c*64+cp];
    }
    if (tid < 192) ws[WOFF_WD1 + tid] = sd1[tid/3]*Wd1[tid];
  } else if (bid == 5) {          // G2T[cp][c]
    for (int e = tid; e < 4096; e += 256) {
      int cp = e >> 6, c = e & 63;
      ws[WOFF_G2T + e] = sg2[c]*Wg2[c*64+cp];
    }
  } else if (bid == 6) {          // Wdn row-major
    for (int e = tid; e < 4096; e += 256) { int o = e >> 6; ws[WOFF_WDN + e] = sdn[o]*Wdn[e]; }
  } else {                        // W_alpha copy
    for (int e = tid; e < 4096; e += 256) ws[WOFF_WAL + e] = Wal[e];
  }
}

// =============== K0b: pack MFMA weights to bf16 row-major [c][cp] ===============
__global__ __launch_bounds__(256) void k0b_pack(float* __restrict__ ws)
{
  const int m = blockIdx.x;                    // 0:Wm 1:Wd2s 2:G2s
  const int srcO = (m==0) ? WOFF_MMT : (m==1) ? WOFF_WD2T : WOFF_G2T;   // [cp][c] fp32
  const int dstO = (m==0) ? WOFF_WMB : (m==1) ? WOFF_WD2B : WOFF_G2B;   // [c][cp] bf16 pairs
  unsigned* dst = (unsigned*)&ws[dstO];
  for (int w = threadIdx.x; w < 2048; w += 256) {
    int c = w >> 5, pair = w & 31;
    float v0 = ws[srcO + (pair*2  )*64 + c];
    float v1 = ws[srcO + (pair*2+1)*64 + c];
    dst[w] = bf2(v0, v1);
  }
}

// =============== K1: per-point features (x -> P1,G1,AL) + r1 + p4 ===============
__global__ __launch_bounds__(256) void k1_feat(const float* __restrict__ inp,
                                               const float* __restrict__ inx,
                                               float* __restrict__ ws)
{
  __shared__ float tX[64][16];   // [c][pt]
  __shared__ float wT[64][64];   // transposed + swizzled weights
  const int tid = threadIdx.x;
  const int pt = tid & 15, q = tid >> 4;   // q in [0,16): channels q*4..q*4+3
  const int gid0 = blockIdx.x * 16;
  const int b = gid0 >> 13, n0 = gid0 & 8191;
  const size_t gq = (size_t)gid0 + pt;

  for (int r = tid; r < 1024; r += 256) {
    int c = r >> 4, col = r & 15;
    tX[c][col] = inx[((size_t)(b*64 + c) << 13) + n0 + col];
  }
  for (int r = tid; r < 4096; r += 256) {
    int o = r >> 6, i = r & 63;
    wT[i][WSWZ(i,o)] = ws[WOFF_WT + r];
  }
  __syncthreads();

  float acc[4];
  #pragma unroll
  for (int i = 0; i < 4; ++i) acc[i] = ws[WOFF_BT + q*4 + i];
  for (int ci = 0; ci < 64; ++ci) {
    float xv = tX[ci][pt];
    const float4 w4 = *(const float4*)&wT[ci][WSWZ(ci, q*4)];
    acc[0] = fmaf(w4.x, xv, acc[0]);
    acc[1] = fmaf(w4.y, xv, acc[1]);
    acc[2] = fmaf(w4.z, xv, acc[2]);
    acc[3] = fmaf(w4.w, xv, acc[3]);
  }
  __syncthreads();
  #pragma unroll
  for (int i = 0; i < 4; ++i) tX[q*4 + i][pt] = acc[i];

  // p4 / p4m + r1 (global only)
  {
    size_t pb = (size_t)b*3*8192 + n0 + pt;
    float px = inp[pb], py = inp[pb + 8192], pz = inp[pb + 16384];
    float sq = __fadd_rn(__fadd_rn(__fmul_rn(px,px), __fmul_rn(py,py)), __fmul_rn(pz,pz));
    if (q == 0) *(float4*)&ws[OFF_P4 + gq*4] = make_float4(px,py,pz,sq);
    if (q == 1) *(float4*)&ws[OFF_P4M + gq*4] = make_float4(-2.f*px, -2.f*py, -2.f*pz, sq);
    float r1v[4];
    #pragma unroll
    for (int i = 0; i < 4; ++i) {
      int c = q*4 + i;
      float a = ws[WOFF_WD1 + c*3+0]*px;
      a = fmaf(ws[WOFF_WD1 + c*3+1], py, a);
      a = fmaf(ws[WOFF_WD1 + c*3+2], pz, a);
      r1v[i] = a;
    }
    *(float4*)&ws[OFF_R1 + gq*64 + q*4] = make_float4(r1v[0], r1v[1], r1v[2], r1v[3]);
  }
  __syncthreads();

  #pragma unroll
  for (int m = 0; m < 3; ++m) {
    const int    mof = (m==0) ? WOFF_P1M : (m==1) ? WOFF_G1M : WOFF_WAL;
    const size_t oof = (m==0) ? OFF_P1   : (m==1) ? OFF_G1   : OFF_AL;
    __syncthreads();
    for (int r = tid; r < 4096; r += 256) {
      int o = r >> 6, i = r & 63;
      wT[i][WSWZ(i,o)] = ws[mof + r];
    }
    __syncthreads();
    #pragma unroll
    for (int i = 0; i < 4; ++i) acc[i] = (m == 2) ? ws[WOFF_BAL + q*4 + i] : 0.f;
    for (int ci = 0; ci < 64; ++ci) {
      float xv = tX[ci][pt];
      const float4 w4 = *(const float4*)&wT[ci][WSWZ(ci, q*4)];
      acc[0] = fmaf(w4.x, xv, acc[0]);
      acc[1] = fmaf(w4.y, xv, acc[1]);
      acc[2] = fmaf(w4.z, xv, acc[2]);
      acc[3] = fmaf(w4.w, xv, acc[3]);
    }
    *(float4*)&ws[oof + gq*64 + q*4] = make_float4(acc[0], acc[1], acc[2], acc[3]);
  }
}

// numpy-exact distance (original operands)
__device__ __forceinline__ float pdist(const float4 q4, const float4 c4) {
  float m = __fadd_rn(__fadd_rn(__fmul_rn(q4.x,c4.x), __fmul_rn(q4.y,c4.y)), __fmul_rn(q4.z,c4.z));
  return __fsub_rn(__fadd_rn(q4.w, c4.w), __fmul_rn(2.f, m));
}

// numpy-exact distance, candidate pre-scaled to (-2x,-2y,-2z,sq):
// scaling by -2 is exact and commutes with fp32 rounding -> bit-identical to pdist.
__device__ __forceinline__ float pdist2(const float4 q4, const float4 c4m) {
  float m = __fadd_rn(__fadd_rn(__fmul_rn(q4.x,c4m.x), __fmul_rn(q4.y,c4m.y)), __fmul_rn(q4.z,c4m.z));
  return __fadd_rn(__fadd_rn(q4.w, c4m.w), m);
}

__device__ __forceinline__ unsigned dmono(float d) {
  unsigned db = __float_as_uint(d);
  return db ^ (((int)db < 0) ? 0xffffffffu : 0x80000000u);
}

// branchless sorted insert into 5-slot ascending list, f32 d-keys via min/max
// + parallel idx via cndmask. '<=' keeps the incumbent on d-ties; within a lane
// stream idx is strictly increasing, so tie order == ascending idx == lex order.
// No NaN possible; all zeros are +0 -> f32 order == dmono-u32 order.
__device__ __forceinline__ void ins5f(float& d0, float& d1, float& d2,
                                      float& d3, float& d4,
                                      unsigned& i0, unsigned& i1, unsigned& i2,
                                      unsigned& i3, unsigned& i4,
                                      float xd, unsigned xi)
{
  float tn; unsigned ti; bool c;
  c = (d0 <= xd);  tn = fminf(d0, xd);  ti = c ? i0 : xi;  xd = fmaxf(d0, xd);  xi = c ? xi : i0;  d0 = tn; i0 = ti;
  c = (d1 <= xd);  tn = fminf(d1, xd);  ti = c ? i1 : xi;  xd = fmaxf(d1, xd);  xi = c ? xi : i1;  d1 = tn; i1 = ti;
  c = (d2 <= xd);  tn = fminf(d2, xd);  ti = c ? i2 : xi;  xd = fmaxf(d2, xd);  xi = c ? xi : i2;  d2 = tn; i2 = ti;
  c = (d3 <= xd);  tn = fminf(d3, xd);  ti = c ? i3 : xi;  xd = fmaxf(d3, xd);  xi = c ? xi : i3;  d3 = tn; i3 = ti;
  c = (d4 <= xd);  d4 = fminf(d4, xd);  i4 = c ? i4 : xi;
}

// =============== K2: exact top-16 KNN, single pass (wave-per-query) ===============
// R15 structure; ladder now f32 min/max (dmono deferred to the 5 survivors) and the
// candidate tile pre-scaled (saves the 2*m multiply; bit-identical distances).
// Soundness unchanged: every dropped element is strictly u64-lex greater than the
// lane's final 5th slot; if all lanes' savedk4 >= m16 the union contains the true
// top-16, else guaranteed serial rescan (on the ORIGINAL P4 data).
__global__ __launch_bounds__(256) void k2_topk(float* __restrict__ ws)
{
  __shared__ float4 tile[1024];   // 16 KB
  const int tid = threadIdx.x;
  const int lane = tid & 63, w = tid >> 6;
  const int gid = blockIdx.x*4 + w;
  const int b = gid >> 13;
  const float4 q4 = *(const float4*)&ws[OFF_P4 + (size_t)gid*4];
  const float4* cp4m = (const float4*)&ws[OFF_P4M + (size_t)b*8192*4];
  int* ib = (int*)&ws[OFF_IDX];

  const float INF = __int_as_float(0x7f800000);
  float d0=INF,d1=INF,d2=INF,d3=INF,d4=INF;
  unsigned i0=~0u,i1=~0u,i2=~0u,i3=~0u,i4=~0u;

  #pragma unroll 1
  for (int c0 = 0; c0 < 8192; c0 += 1024) {
    __syncthreads();
    #pragma unroll
    for (int t = 0; t < 4; ++t) tile[tid + t*256] = cp4m[c0 + tid + t*256];
    __syncthreads();
    #pragma unroll 8
    for (int r = 0; r < 16; ++r) {
      const int ci = r*64 + lane;
      float d = pdist2(q4, tile[ci]);
      ins5f(d0,d1,d2,d3,d4, i0,i1,i2,i3,i4, d, (unsigned)(c0 + ci));
    }
  }

  // rebuild u64 keys for the 5 survivors
  unsigned long long k0 = ((unsigned long long)dmono(d0) << 32) | i0;
  unsigned long long k1 = ((unsigned long long)dmono(d1) << 32) | i1;
  unsigned long long k2 = ((unsigned long long)dmono(d2) << 32) | i2;
  unsigned long long k3 = ((unsigned long long)dmono(d3) << 32) | i3;
  unsigned long long k4 = ((unsigned long long)dmono(d4) << 32) | i4;
  const unsigned long long savedk4 = k4;

  // 16 wave-argmin rounds over the 320-key union (5 keys/lane)
  unsigned myres = 0u;
  unsigned long long m = 0ull;
  #pragma unroll 1
  for (int r = 0; r < 16; ++r) {
    unsigned long long a01 = (k0 < k1) ? k0 : k1;
    unsigned long long a23 = (k2 < k3) ? k2 : k3;
    unsigned long long a03 = (a01 < a23) ? a01 : a23;
    m = (a03 < k4) ? a03 : k4;
    #pragma unroll
    for (int s = 1; s < 64; s <<= 1) {
      unsigned long long o = __shfl_xor(m, s);
      m = (o < m) ? o : m;
    }
    k0 = (k0 == m) ? ~0ull : k0;  k1 = (k1 == m) ? ~0ull : k1;
    k2 = (k2 == m) ? ~0ull : k2;  k3 = (k3 == m) ? ~0ull : k3;
    k4 = (k4 == m) ? ~0ull : k4;
    if (lane == r) myres = (unsigned)(m & 0xffffffffu);
  }

  // safety check: m (last round) is the 16th-smallest of the union
  const bool unsafe = __ballot(savedk4 < m) != 0ull;
  if (!unsafe) {
    if (lane < 16) ib[(size_t)gid*16 + lane] = (int)myres;
  } else {
    // guaranteed-correct fallback (~2.6e-4 per query): serial rescan on original P4
    if (lane == 0) {
      const float4* cp4 = (const float4*)&ws[OFF_P4 + (size_t)b*8192*4];
      float ds[16]; int is[16];
      #pragma unroll
      for (int r = 0; r < 16; ++r) { ds[r] = FLT_MAX; is[r] = 0x7fffffff; }
      for (int t = 0; t < 8192; ++t) {
        float d = pdist(q4, cp4[t]);
        if (d < ds[15]) {
          #pragma unroll
          for (int s = 15; s >= 0; --s) {
            bool bs = d < ds[s];
            bool bm = (s > 0) ? (d < ds[s-1]) : false;
            float dn = bs ? (bm ? ds[s-1] : d) : ds[s];
            int   jn = bs ? (bm ? is[s-1] : t) : is[s];
            ds[s] = dn; is[s] = jn;
          }
        }
      }
      #pragma unroll
      for (int r = 0; r < 16; ++r) ib[(size_t)gid*16 + r] = is[r];
    }
  }
}

// =============== K3 (MFMA): fused per-point block (weights in LDS, 16 pts/block) ===============
__global__ __launch_bounds__(256) void k3_mfma(float* __restrict__ ws, float* __restrict__ out)
{
  __shared__ __align__(16) unsigned char wL[24576];  // 3 x [64 c][64 cp] bf16, swizzled
  __shared__ __align__(16) unsigned char hL[32768];  // [256 col][64 cp] bf16, swizzled
  const int tid = threadIdx.x;
  const int lane = tid & 63, wid = tid >> 6;
  const int l15 = lane & 15, hi = lane >> 4;
  const int gid0 = blockIdx.x * 16;       // first global point of block
  const int b = gid0 >> 13;
  const int n0 = gid0 & 8191;

  // ---- stage bf16 weights into LDS (swizzled rows) ----
  {
    const uint4* wsrc = (const uint4*)&ws[WOFF_WMB];
    for (int t = tid; t < 1536; t += 256) {
      int m = t >> 9, r = t & 511;
      int c = r >> 3, q = r & 7;
      uint4 v = wsrc[t];
      *(uint4*)(wL + m*8192 + ((c*128 + q*16) ^ ((c&7)<<4))) = v;
    }
  }
  // ---- compute h for own column (col = tid) ----
  {
    const int pt = tid >> 4, kq = tid & 15;
    const size_t gq = (size_t)gid0 + pt;
    const int jh = ((const int*)&ws[OFF_IDX])[gq*16 + kq];
    const size_t gjh = (size_t)b*8192 + jh;
    const float4* Ar = (const float4*)&ws[OFF_R1 + gq*64];
    const float4* Br = (const float4*)&ws[OFF_R1 + gjh*64];
    const float4* Ur = (const float4*)&ws[WOFF_UD1];
    const int swzh = (tid & 7) << 4;
    #pragma unroll
    for (int t = 0; t < 16; ++t) {
      float4 a = Ar[t], bb = Br[t], u = Ur[t];
      float v0 = fmaxf(a.x - bb.x + u.x, 0.f);
      float v1 = fmaxf(a.y - bb.y + u.y, 0.f);
      float v2 = fmaxf(a.z - bb.z + u.z, 0.f);
      float v3 = fmaxf(a.w - bb.w + u.w, 0.f);
      *(uint2*)(hL + ((tid*128 + t*8) ^ swzh)) = make_uint2(bf2(v0,v1), bf2(v2,v3));
    }
  }
  __syncthreads();

  float* attnp = out + (size_t)2*64*8192;   // attn region after out0
  const f32x4 zf = {0.f, 0.f, 0.f, 0.f};

  for (int i = 0; i < 4; ++i) {
    const int ct = (wid << 2) + i;          // coltile == point index in block
    const int n = n0 + ct;
    const size_t gqc = (size_t)gid0 + ct;
    const int mycol = (ct << 4) + l15;
    const int swz = (mycol & 7) << 4;
    const int hbase = mycol*128 + hi*16;
    bf16x8 hb0 = *(const bf16x8*)(hL + ((hbase     ) ^ swz));
    bf16x8 hb1 = *(const bf16x8*)(hL + ((hbase + 64) ^ swz));
    const int jj = ((const int*)&ws[OFF_IDX])[gqc*16 + l15];
    const size_t gjc = (size_t)b*8192 + jj;

    // ---- D-GEMM (pos) + M-GEMM ----
    f32x4 accD[4], accM[4];
    #pragma unroll
    for (int rt = 0; rt < 4; ++rt) { accD[rt] = zf; accM[rt] = zf; }
    #pragma unroll
    for (int rt = 0; rt < 4; ++rt) {
      const int c = (rt << 4) + l15;
      const int ws2 = (c & 7) << 4;
      const int wb = c*128 + hi*16;
      bf16x8 m0 = *(const bf16x8*)(wL + (((wb     ) ^ ws2)));
      bf16x8 m1 = *(const bf16x8*)(wL + (((wb + 64) ^ ws2)));
      bf16x8 d0 = *(const bf16x8*)(wL + (8192 + ((wb     ) ^ ws2)));
      bf16x8 d1 = *(const bf16x8*)(wL + (8192 + ((wb + 64) ^ ws2)));
      accM[rt] = __builtin_amdgcn_mfma_f32_16x16x32_bf16(m0, hb0, accM[rt], 0, 0, 0);
      accM[rt] = __builtin_amdgcn_mfma_f32_16x16x32_bf16(m1, hb1, accM[rt], 0, 0, 0);
      accD[rt] = __builtin_amdgcn_mfma_f32_16x16x32_bf16(d0, hb0, accD[rt], 0, 0, 0);
      accD[rt] = __builtin_amdgcn_mfma_f32_16x16x32_bf16(d1, hb1, accD[rt], 0, 0, 0);
    }

    // ---- hg = relu(aM + P1[n] - G1[j] + vc), write bf16 back into hL (in place) ----
    #pragma unroll
    for (int rt = 0; rt < 4; ++rt) {
      const int c0 = (rt << 4) + (hi << 2);
      const float4 p1 = *(const float4*)&ws[OFF_P1 + gqc*64 + c0];
      const float4 g1 = *(const float4*)&ws[OFF_G1 + gjc*64 + c0];
      const float4 vc = *(const float4*)&ws[WOFF_VC + c0];
      float h0 = fmaxf(accM[rt][0] + p1.x - g1.x + vc.x, 0.f);
      float h1 = fmaxf(accM[rt][1] + p1.y - g1.y + vc.y, 0.f);
      float h2 = fmaxf(accM[rt][2] + p1.z - g1.z + vc.z, 0.f);
      float h3 = fmaxf(accM[rt][3] + p1.w - g1.w + vc.w, 0.f);
      *(uint2*)(hL + ((mycol*128 + (c0 << 1)) ^ swz)) = make_uint2(bf2(h0,h1), bf2(h2,h3));
    }

    // ---- G2-GEMM on hg (wave-local; DS ops are in-order within a wave) ----
    bf16x8 gb0 = *(const bf16x8*)(hL + ((hbase     ) ^ swz));
    bf16x8 gb1 = *(const bf16x8*)(hL + ((hbase + 64) ^ swz));
    f32x4 accG[4];
    #pragma unroll
    for (int rt = 0; rt < 4; ++rt) accG[rt] = zf;
    #pragma unroll
    for (int rt = 0; rt < 4; ++rt) {
      const int c = (rt << 4) + l15;
      const int ws2 = (c & 7) << 4;
      const int wb = c*128 + hi*16;
      bf16x8 g0 = *(const bf16x8*)(wL + (16384 + ((wb     ) ^ ws2)));
      bf16x8 g1f = *(const bf16x8*)(wL + (16384 + ((wb + 64) ^ ws2)));
      accG[rt] = __builtin_amdgcn_mfma_f32_16x16x32_bf16(g0,  gb0, accG[rt], 0, 0, 0);
      accG[rt] = __builtin_amdgcn_mfma_f32_16x16x32_bf16(g1f, gb1, accG[rt], 0, 0, 0);
    }

    // ---- softmax over kk (lane&15), attn store, y reduce ----
    #pragma unroll
    for (int rt = 0; rt < 4; ++rt) {
      const int c0 = (rt << 4) + (hi << 2);
      const float4 al = *(const float4*)&ws[OFF_AL + gjc*64 + c0];
      const float4 u2 = *(const float4*)&ws[WOFF_UD2 + c0];
      float y4[4];
      #pragma unroll
      for (int r = 0; r < 4; ++r) {
        float g = accG[rt][r];
        float mx = g;
        mx = fmaxf(mx, __shfl_xor(mx, 1));
        mx = fmaxf(mx, __shfl_xor(mx, 2));
        mx = fmaxf(mx, __shfl_xor(mx, 4));
        mx = fmaxf(mx, __shfl_xor(mx, 8));
        float e = __expf(g - mx);
        float sm = e;
        sm += __shfl_xor(sm, 1);
        sm += __shfl_xor(sm, 2);
        sm += __shfl_xor(sm, 4);
        sm += __shfl_xor(sm, 8);
        float rs;
        asm("v_rcp_f32 %0, %1" : "=v"(rs) : "v"(sm));
        float a = e * rs;
        attnp[(((size_t)(b*64 + c0 + r) << 13) + n)*16 + l15] = a;
        float pv = ((const float*)&al)[r] + accD[rt][r] + ((const float*)&u2)[r];
        float yv = a * pv;
        yv += __shfl_xor(yv, 1);
        yv += __shfl_xor(yv, 2);
        yv += __shfl_xor(yv, 4);
        yv += __shfl_xor(yv, 8);
        y4[r] = yv;
      }
      if (l15 == 0)
        *(float4*)&ws[OFF_Y + gqc*64 + c0] = make_float4(y4[0], y4[1], y4[2], y4[3]);
    }
  }
}

// =============== K4: out = Wdn*y + udn + input_x ===============
__global__ __launch_bounds__(256) void k4_out(const float* __restrict__ inx,
                                              float* __restrict__ ws,
                                              float* __restrict__ out)
{
  __shared__ float yS[16][64];
  __shared__ float wT[64][64];
  const int tid = threadIdx.x;
  const int pt = tid & 15, q = tid >> 4;   // channels q*4..q*4+3
  const int gid0 = blockIdx.x*16;
  const int b = gid0 >> 13, n0 = gid0 & 8191;
  for (int r = tid; r < 1024; r += 256) {
    int p2 = r >> 6, c = r & 63;
    yS[p2][c ^ p2] = ws[OFF_Y + (size_t)(gid0 + p2)*64 + c];
  }
  for (int r = tid; r < 4096; r += 256) {
    int o = r >> 6, i = r & 63;
    wT[i][WSWZ(i,o)] = ws[WOFF_WDN + r];
  }
  __syncthreads();
  float acc[4];
  #pragma unroll
  for (int i = 0; i < 4; ++i) acc[i] = ws[WOFF_UDN + q*4 + i];
  for (int ci = 0; ci < 64; ++ci) {
    float yv = yS[pt][ci ^ pt];
    const float4 w4 = *(const float4*)&wT[ci][WSWZ(ci, q*4)];
    acc[0] = fmaf(w4.x, yv, acc[0]);
    acc[1] = fmaf(w4.y, yv, acc[1]);
    acc[2] = fmaf(w4.z, yv, acc[2]);
    acc[3] = fmaf(w4.w, yv, acc[3]);
  }
  #pragma unroll
  for (int i = 0; i < 4; ++i) {
    const int c = q*4 + i;
    size_t o = ((size_t)(b*64 + c) << 13) + n0 + pt;
    out[o] = acc[i] + inx[o];
  }
}

extern "C" void kernel_launch(void* const* d_in, const int* in_sizes, int n_in,
                              void* d_out, int out_size, void* d_ws, size_t ws_size,
                              hipStream_t stream)
{
  (void)in_sizes; (void)n_in; (void)out_size; (void)ws_size;
  float* ws = (float*)d_ws;
  const float* inp = (const float*)d_in[0];
  const float* inx = (const float*)d_in[1];
  float* out = (float*)d_out;
  P32 P;
  for (int i = 0; i < 32; ++i) P.a[i] = (const float*)d_in[i];

  k0_fold   <<<8,      256, 0, stream>>>(P, ws);
  k0b_pack  <<<3,      256, 0, stream>>>(ws);
  k1_feat   <<<BN/16,  256, 0, stream>>>(inp, inx, ws);
  k2_topk   <<<BN/4,   256, 0, stream>>>(ws);
  k3_mfma   <<<BN/16,  256, 0, stream>>>(ws, out);
  k4_out    <<<BN/16,  256, 0, stream>>>(inx, ws, out);
}